// Round 8
// baseline (2417.884 us; speedup 1.0000x reference)
//
#include <hip/hip_runtime.h>
#include <hip/hip_bf16.h>
#include <cstddef>
#include <cstdint>

#define LEAK  0.99f
#define THRS  1.0f
#define BNEPS 1e-4f

static constexpr int TT   = 8;
static constexpr int BB   = 4;
static constexpr int NCLS = 21;

typedef __attribute__((ext_vector_type(8))) short short8v;   // 8 bf16 (MFMA A/B frag)
typedef __attribute__((ext_vector_type(4))) float f32x4;     // MFMA C/D frag

__global__ void zero_f32(float* __restrict__ p, int n) {
  int i = blockIdx.x * blockDim.x + threadIdx.x;
  int stride = gridDim.x * blockDim.x;
  for (; i < n; i += stride) p[i] = 0.0f;
}

__global__ void scale_f32(float* __restrict__ p, int n, float s) {
  int i = blockIdx.x * blockDim.x + threadIdx.x;
  if (i < n) p[i] *= s;
}

// Split f32 weights (scaled) into hi+lo bf16, reordered to k = tap*Cip + ci.
__global__ void wsplit(const float* __restrict__ Wsrc,
                       __hip_bfloat16* __restrict__ whi, __hip_bfloat16* __restrict__ wlo,
                       int Co, int Ci, int Cip, float scale) {
  const int Kpad = 9 * Cip;
  const int n = Co * Kpad;
  int i = blockIdx.x * 256 + threadIdx.x;
  if (i >= n) return;
  int co = i / Kpad, k = i - co * Kpad;
  int tap = k / Cip, ci = k - tap * Cip;
  float w = 0.0f;
  if (ci < Ci) w = Wsrc[((size_t)co * Ci + ci) * 9 + tap] * scale;
  __hip_bfloat16 h = __float2bfloat16(w);
  float r = w - __bfloat162float(h);
  whi[i] = h;
  wlo[i] = __float2bfloat16(r);
}

// Poisson generator, writes channel-last [B][HW][32] (ch 3..31 pre-zeroed each call)
__global__ void spike_gen(const float* __restrict__ x, const float* __restrict__ u,
                          __hip_bfloat16* __restrict__ spk) {
  const int HW = 128 * 128;
  int i = blockIdx.x * 256 + threadIdx.x;  // b*HW + hw
  if (i >= BB * HW) return;
  int b = i / HW, hw = i - b * HW;
#pragma unroll
  for (int c = 0; c < 3; ++c) {
    float xv = x[((size_t)b * 3 + c) * HW + hw];
    float uv = u[((size_t)b * 3 + c) * HW + hw];
    float ax = fabsf(xv);
    float sg = (xv > 0.0f) ? 1.0f : ((xv < 0.0f) ? -1.0f : 0.0f);
    float s  = (uv <= ax) ? sg : 0.0f;
    spk[(size_t)i * 32 + c] = __float2bfloat16(s);
  }
}

// Implicit-GEMM conv3x3(pad==dil) + BN + LIF.  MFMA 16x16x32 bf16, hi+lo weight split.
// Wave tile (M*16 px) x (N*16 co); block = 4 waves px-stacked.
// Group pipeline with COUNTED vmcnt: each group top does
//   s_waitcnt vmcnt(M*GRP) -> my stage(gi) (issued a full group ago) landed, prefA still in flight
//   s_barrier + sched_barrier(0)
// A-prefetch alternates static register arrays aA/aB (no copies, no vmcnt(0) drain).
// OOB conv taps read a zeroed page (address select per tap, no per-chunk cndmask).
// px-major wave tiles (bigger M) cut LDS B-bytes and ds_read issue slots per FLOP.
template<int M, int N, int GRP>
__global__ __launch_bounds__(256) void gemm_lif(
    const __hip_bfloat16* __restrict__ actin,
    const __hip_bfloat16* __restrict__ wsp,      // [2][Co][Kpad] hi, lo
    const float* __restrict__ bnt,               // [3][Co] for this timestep
    float* __restrict__ mem, __hip_bfloat16* __restrict__ actout,
    const __hip_bfloat16* __restrict__ zp,       // zero page (>= Cip+32 bf16, zeroed)
    int Cip, int Co, int lgHW, int lgW, int dil, int lgGX) {
  constexpr int NW = 4;
  constexpr int R  = N * 32;                 // LDS rows per chunk (hi+lo halves)
  constexpr int lgR = (N == 1) ? 5 : ((N == 2) ? 6 : 7);
  constexpr int BUFROWS = GRP * R;
  constexpr int BUFELEM = BUFROWS * 32;      // bf16 elems per buffer
  constexpr int INSTS = BUFROWS / (16 * NW); // global_load_lds per wave per group
  constexpr int AM = M * GRP;                // A-prefetch vm ops per group
  __shared__ __hip_bfloat16 lds[2 * BUFELEM];

  const int HW = 1 << lgHW, H = HW >> lgW, W = 1 << lgW;
  const int Kpad = 9 * Cip;
  const unsigned CoKpad = (unsigned)Co * Kpad;
  const int lane = threadIdx.x & 63, wid = threadIdx.x >> 6;
  const int l15 = lane & 15, g = lane >> 4;

  // XCD-chunked bijective block swizzle (gridDim.x % 8 == 0)
  const int nb = gridDim.x;
  const int flat = blockIdx.x;
  const int swz = (flat & 7) * (nb >> 3) + (flat >> 3);
  const int bx = swz & ((1 << lgGX) - 1);
  const int by = swz >> lgGX;
  const int p0  = (bx * NW + wid) * (M * 16);
  const int co0 = by * (N * 16);

  // per-m-frag pixel decompose (16 consecutive px stay in one image row)
  int b_[M], y_[M], x_[M];
#pragma unroll
  for (int m = 0; m < M; ++m) {
    int pb = p0 + m * 16;
    b_[m] = pb >> lgHW;
    int rem = pb & (HW - 1);
    y_[m] = rem >> lgW;
    x_[m] = (rem & (W - 1)) + l15;
  }

  // weight staging source addrs (LDS dest linear; swizzle on GLOBAL source:
  // LDS slot s of row co holds global slot s ^ ((co>>1)&3))
  unsigned sgb[INSTS];
#pragma unroll
  for (int i = 0; i < INSTS; ++i) {
    int f  = wid * (BUFROWS / NW) + i * 16 + (lane >> 2);  // flat row in group
    int cc = f >> lgR;                // chunk within group
    int r  = f & (R - 1);             // row within chunk
    int half = r >> (lgR - 1);        // 0 = hi, 1 = lo  (16N rows each)
    int co   = r & (16 * N - 1);
    int slot = (lane & 3) ^ ((co >> 1) & 3);
    sgb[i] = (unsigned)half * CoKpad + (unsigned)(co0 + co) * Kpad + slot * 8 + cc * 32;
  }

  auto stage = [&](int grp, int buf) {
#pragma unroll
    for (int i = 0; i < INSTS; ++i) {
      const __hip_bfloat16* gp = wsp + sgb[i] + grp * (GRP * 32);
      __hip_bfloat16* lp = &lds[buf * BUFELEM + (wid * (BUFROWS / NW) + i * 16) * 32];
      __builtin_amdgcn_global_load_lds(
          (const __attribute__((address_space(1))) void*)gp,
          (__attribute__((address_space(3))) void*)lp, 16, 0, 0);
    }
  };

  const int cpt = Cip >> 5;            // chunks per tap (power of 2)
  const int lgcpt = __builtin_ctz(cpt);
  const int NGRP = (9 * cpt) / GRP;

  // rolling per-tap A addressing; OOB -> zero page (no per-chunk select needed)
  const __hip_bfloat16* apc[M];
  auto mkaddr = [&](int tap) {
    int ty = (tap * 11) >> 5;          // tap/3 for 0..8
    int tx = tap - ty * 3;
    int dy = (ty - 1) * dil, dx = (tx - 1) * dil;
#pragma unroll
    for (int m = 0; m < M; ++m) {
      int sy = y_[m] + dy, sx = x_[m] + dx;
      bool v = (sy >= 0) & (sy < H) & (sx >= 0) & (sx < W);
      int pix = (b_[m] << lgHW) + (sy << lgW) + sx;
      apc[m] = v ? (actin + (size_t)pix * Cip + 8 * g) : (zp + 8 * g);
    }
  };

  auto prefA = [&](int grp, short8v (&dst)[GRP][M]) {
#pragma unroll
    for (int cc = 0; cc < GRP; ++cc) {
      int c = grp * GRP + cc;
      if ((c & (cpt - 1)) == 0) mkaddr(c >> lgcpt);   // wave-uniform
      int kc = (c & (cpt - 1)) << 5;
#pragma unroll
      for (int m = 0; m < M; ++m)
        dst[cc][m] = *(const short8v*)(apc[m] + kc);
    }
  };

  f32x4 acc[M][N] = {};
  const int rdb = l15 * 32 + ((g ^ ((l15 >> 1) & 3)) * 8);  // swizzled read base

  short8v aA[GRP][M], aB[GRP][M];

  // one pipeline group: wait my stage(gi) landed (counted), barrier, issue next
  // group's stage+prefA, then ds_read + MFMA on aU.
  auto grp_body = [&](int gi, short8v (&aU)[GRP][M], short8v (&aF)[GRP][M]) {
    asm volatile("s_waitcnt vmcnt(%0)" :: "n"(AM) : "memory");
    __builtin_amdgcn_s_barrier();
    __builtin_amdgcn_sched_barrier(0);

    if (gi + 1 < NGRP) {
      stage(gi + 1, (gi + 1) & 1);
      prefA(gi + 1, aF);
    }

    const __hip_bfloat16* bp = &lds[(gi & 1) * BUFELEM];
#pragma unroll
    for (int cc = 0; cc < GRP; ++cc) {
      short8v bh[N], bl[N];
#pragma unroll
      for (int j = 0; j < N; ++j) {
        bh[j] = *(const short8v*)(bp + cc * (R * 32) + j * 512 + rdb);
        bl[j] = *(const short8v*)(bp + cc * (R * 32) + (N * 512) + j * 512 + rdb);
      }
      __builtin_amdgcn_s_setprio(1);
#pragma unroll
      for (int j = 0; j < N; ++j)
#pragma unroll
        for (int m = 0; m < M; ++m) {
          acc[m][j] = __builtin_amdgcn_mfma_f32_16x16x32_bf16(aU[cc][m], bh[j], acc[m][j], 0, 0, 0);
          acc[m][j] = __builtin_amdgcn_mfma_f32_16x16x32_bf16(aU[cc][m], bl[j], acc[m][j], 0, 0, 0);
        }
      __builtin_amdgcn_s_setprio(0);
    }
  };

  // prologue: group 0
  stage(0, 0);
  prefA(0, aA);

  int gi = 0;
  while (gi < NGRP) {
    grp_body(gi, aA, aB); ++gi;
    if (gi < NGRP) { grp_body(gi, aB, aA); ++gi; }
  }

  // epilogue: BN + LIF.  D: co = co0 + j*16 + l15, pixel = p0 + m*16 + 4g + r
#pragma unroll
  for (int j = 0; j < N; ++j) {
    int c = co0 + j * 16 + l15;
    float ga = bnt[c], mu = bnt[Co + c], va = bnt[2 * Co + c];
    float sc = ga / sqrtf(va + BNEPS);
#pragma unroll
    for (int m = 0; m < M; ++m) {
      int pixb = p0 + m * 16 + 4 * g;
#pragma unroll
      for (int r = 0; r < 4; ++r) {
        size_t idx = (size_t)(pixb + r) * Co + c;
        float bno = (acc[m][j][r] - mu) * sc;
        float mv = LEAK * mem[idx] + bno;
        float s = (mv > THRS) ? 1.0f : 0.0f;
        actout[idx] = __float2bfloat16(s);
        mem[idx] = mv - s;
      }
    }
  }
}

// AvgPool(3,2,1) storing SUM (exact ints in bf16); /9 folded into next layer weights.
// channel-last, vectorized: one thread = 8 channels of one output pixel.
__global__ void avgpool_sum8(const __hip_bfloat16* __restrict__ in,
                             __hip_bfloat16* __restrict__ out, int C, int H, int W) {
  const int Ho = H >> 1, Wo = W >> 1;
  const int C8 = C >> 3;
  const int n = BB * Ho * Wo * C8;
  int i = blockIdx.x * 256 + threadIdx.x;
  if (i >= n) return;
  int c8 = i % C8; int t = i / C8;
  int xo = t % Wo; t /= Wo;
  int yo = t % Ho; int b = t / Ho;
  const int y0 = 2 * yo - 1, x0 = 2 * xo - 1;
  float s[8] = {0, 0, 0, 0, 0, 0, 0, 0};
#pragma unroll
  for (int dy = 0; dy < 3; ++dy) {
    int iy = y0 + dy;
    if (iy < 0 || iy >= H) continue;
#pragma unroll
    for (int dx = 0; dx < 3; ++dx) {
      int ix = x0 + dx;
      if (ix < 0 || ix >= W) continue;
      short8v v = *(const short8v*)(in + (((size_t)b * H + iy) * W + ix) * C + c8 * 8);
#pragma unroll
      for (int e = 0; e < 8; ++e) {
        __hip_bfloat16_raw raw; raw.x = (unsigned short)v[e];
        s[e] += __bfloat162float(__hip_bfloat16(raw));
      }
    }
  }
  short8v o;
#pragma unroll
  for (int e = 0; e < 8; ++e) {
    __hip_bfloat16_raw raw = __hip_bfloat16_raw(__float2bfloat16(s[e]));
    o[e] = (short)raw.x;
  }
  *(short8v*)(out + (size_t)i * 8) = o;
}

// 1x1 conv 1024->21 @32x32, f32, accumulate into d_out. One wave per (b,pix).
__global__ void out_conv(const __hip_bfloat16* __restrict__ act,  // [B*1024px][1024ch]
                         const float* __restrict__ W8, float* __restrict__ out) {
  int gw = (blockIdx.x * 256 + threadIdx.x) >> 6;  // b*1024 + pix
  int lane = threadIdx.x & 63;
  int b = gw >> 10, pix = gw & 1023;
  const __hip_bfloat16* ap = act + ((size_t)gw << 10);
  float acc[NCLS];
#pragma unroll
  for (int c = 0; c < NCLS; ++c) acc[c] = 0.0f;
  for (int j = 0; j < 16; ++j) {
    int ci = j * 64 + lane;
    float av = __bfloat162float(ap[ci]);
#pragma unroll
    for (int c = 0; c < NCLS; ++c) acc[c] = fmaf(av, W8[c * 1024 + ci], acc[c]);
  }
#pragma unroll
  for (int c = 0; c < NCLS; ++c) {
    float v = acc[c];
    for (int off = 32; off; off >>= 1) v += __shfl_xor(v, off, 64);
    if (lane == 0) out[((size_t)b * NCLS + c) * 1024 + pix] += v;
  }
}

extern "C" void kernel_launch(void* const* d_in, const int* in_sizes, int n_in,
                              void* d_out, int out_size, void* d_ws, size_t ws_size,
                              hipStream_t stream) {
  const float* x = (const float*)d_in[0];
  const float* u = (const float*)d_in[1];
  const float* Wc[9];
  for (int i = 0; i < 9; ++i) Wc[i] = (const float*)d_in[2 + i];
  const float* bn[8];
  for (int i = 0; i < 8; ++i) bn[i] = (const float*)d_in[11 + i];

  const int Ci_[8]  = {3, 64, 64, 128, 128, 256, 256, 256};
  const int Cip_[8] = {32, 64, 64, 128, 128, 256, 256, 256};
  const int Co_[8]  = {64, 64, 128, 128, 256, 256, 256, 1024};
  const int HH_[8]  = {128, 128, 64, 64, 32, 32, 32, 32};
  const float wsc_[8] = {1.f, 1.f, 1.f / 9.f, 1.f, 1.f / 9.f, 1.f, 1.f, 1.f};

  float* ws = (float*)d_ws;
  size_t off = 0;
  auto align8 = [](size_t v) { return (v + 7) & ~(size_t)7; };

  float* memp[8];
  for (int i = 0; i < 8; ++i) {
    memp[i] = ws + off;
    off += (size_t)BB * HH_[i] * HH_[i] * Co_[i];
  }
  __hip_bfloat16* spk = (__hip_bfloat16*)(ws + off);
  off += (size_t)BB * 16384 * 32 / 2;
  __hip_bfloat16* zp = (__hip_bfloat16*)(ws + off);   // zero page (1 KB)
  off += 256;
  const size_t zero_floats = off;                     // mem + spk + zp zeroed each call
  __hip_bfloat16* actA = (__hip_bfloat16*)(ws + off); off += 2097152;
  __hip_bfloat16* actB = (__hip_bfloat16*)(ws + off); off += 2097152;
  __hip_bfloat16* wall[8];
  for (int i = 0; i < 8; ++i) {
    size_t n = (size_t)Co_[i] * 9 * Cip_[i];            // per half
    wall[i] = (__hip_bfloat16*)(ws + off);
    off = align8(off + n);                              // hi + lo = n floats
  }

  zero_f32<<<2048, 256, 0, stream>>>(ws, (int)zero_floats);
  zero_f32<<<(BB * NCLS * 1024 + 255) / 256, 256, 0, stream>>>((float*)d_out, BB * NCLS * 1024);

  for (int i = 0; i < 8; ++i) {
    int n = Co_[i] * 9 * Cip_[i];
    wsplit<<<(n + 255) / 256, 256, 0, stream>>>(Wc[i], wall[i], wall[i] + n,
                                                Co_[i], Ci_[i], Cip_[i], wsc_[i]);
  }

  const size_t uT = (size_t)BB * 3 * 16384;
  for (int t = 0; t < TT; ++t) {
    spike_gen<<<(BB * 16384 + 255) / 256, 256, 0, stream>>>(x, u + (size_t)t * uT, spk);
    // L0: 3(32)->64 @128   wave 32x64, block 128px x 64co, grid 512
    gemm_lif<2, 4, 3><<<512, 256, 0, stream>>>(spk,  wall[0], bn[0] + (size_t)t * 3 * 64,   memp[0], actA, zp, 32,  64,   14, 7, 1, 9);
    // L1: 64->64 @128      wave 64x32 (px-major), block 256px x 32co, grid 256x2
    gemm_lif<4, 2, 2><<<512, 256, 0, stream>>>(actA, wall[1], bn[1] + (size_t)t * 3 * 64,   memp[1], actB, zp, 64,  64,   14, 7, 1, 8);
    avgpool_sum8<<<(BB * 64 * 64 * 8 + 255) / 256, 256, 0, stream>>>(actB, actA, 64, 128, 128);
    // L2: 64->128 @64 (weights pre-scaled 1/9)  wave 32x32, grid 128x4
    gemm_lif<2, 2, 3><<<512, 256, 0, stream>>>(actA, wall[2], bn[2] + (size_t)t * 3 * 128,  memp[2], actB, zp, 64,  128,  12, 6, 1, 7);
    // L3: 128->128 @64
    gemm_lif<2, 2, 4><<<512, 256, 0, stream>>>(actB, wall[3], bn[3] + (size_t)t * 3 * 128,  memp[3], actA, zp, 128, 128,  12, 6, 1, 7);
    avgpool_sum8<<<(BB * 32 * 32 * 16 + 255) / 256, 256, 0, stream>>>(actA, actB, 128, 64, 64);
    // L4: 128->256 @32 (weights pre-scaled 1/9)  wave 32x16 (px-major), grid 32x16
    gemm_lif<2, 1, 4><<<512, 256, 0, stream>>>(actB, wall[4], bn[4] + (size_t)t * 3 * 256,   memp[4], actA, zp, 128, 256,  10, 5, 1, 5);
    // L5: 256->256 @32 dil2  wave 32x16
    gemm_lif<2, 1, 4><<<512, 256, 0, stream>>>(actA, wall[5], bn[5] + (size_t)t * 3 * 256,   memp[5], actB, zp, 256, 256,  10, 5, 2, 5);
    // L6: 256->256 @32 dil2
    gemm_lif<2, 1, 4><<<512, 256, 0, stream>>>(actB, wall[6], bn[6] + (size_t)t * 3 * 256,   memp[6], actA, zp, 256, 256,  10, 5, 2, 5);
    // L7: 256->1024 @32 dil12  wave 64x32 (px-major), block 256px x 32co, grid 16x32
    gemm_lif<4, 2, 2><<<512, 256, 0, stream>>>(actA, wall[7], bn[7] + (size_t)t * 3 * 1024, memp[7], actB, zp, 256, 1024, 10, 5, 12, 4);
    // output layer accumulation
    out_conv<<<dim3(BB * 1024 / 4), 256, 0, stream>>>(actB, Wc[8], (float*)d_out);
  }
  scale_f32<<<(BB * NCLS * 1024 + 255) / 256, 256, 0, stream>>>((float*)d_out, BB * NCLS * 1024, 1.0f / TT);
}

// Round 9
// 2069.892 us; speedup vs baseline: 1.1681x; 1.1681x over previous
//
#include <hip/hip_runtime.h>
#include <hip/hip_bf16.h>
#include <cstddef>
#include <cstdint>

#define LEAK  0.99f
#define THRS  1.0f
#define BNEPS 1e-4f

static constexpr int TT   = 8;
static constexpr int BB   = 4;
static constexpr int NCLS = 21;

typedef __attribute__((ext_vector_type(8))) short short8v;   // 8 bf16 (MFMA A/B frag)
typedef __attribute__((ext_vector_type(4))) float f32x4;     // MFMA C/D frag

__global__ void zero_f32(float* __restrict__ p, int n) {
  int i = blockIdx.x * blockDim.x + threadIdx.x;
  int stride = gridDim.x * blockDim.x;
  for (; i < n; i += stride) p[i] = 0.0f;
}

__global__ void scale_f32(float* __restrict__ p, int n, float s) {
  int i = blockIdx.x * blockDim.x + threadIdx.x;
  if (i < n) p[i] *= s;
}

// Split f32 weights (scaled) into hi+lo bf16, reordered to k = tap*Cip + ci.
__global__ void wsplit(const float* __restrict__ Wsrc,
                       __hip_bfloat16* __restrict__ whi, __hip_bfloat16* __restrict__ wlo,
                       int Co, int Ci, int Cip, float scale) {
  const int Kpad = 9 * Cip;
  const int n = Co * Kpad;
  int i = blockIdx.x * 256 + threadIdx.x;
  if (i >= n) return;
  int co = i / Kpad, k = i - co * Kpad;
  int tap = k / Cip, ci = k - tap * Cip;
  float w = 0.0f;
  if (ci < Ci) w = Wsrc[((size_t)co * Ci + ci) * 9 + tap] * scale;
  __hip_bfloat16 h = __float2bfloat16(w);
  float r = w - __bfloat162float(h);
  whi[i] = h;
  wlo[i] = __float2bfloat16(r);
}

// Poisson generator, writes channel-last [B][HW][32] (ch 3..31 pre-zeroed each call)
__global__ void spike_gen(const float* __restrict__ x, const float* __restrict__ u,
                          __hip_bfloat16* __restrict__ spk) {
  const int HW = 128 * 128;
  int i = blockIdx.x * 256 + threadIdx.x;  // b*HW + hw
  if (i >= BB * HW) return;
  int b = i / HW, hw = i - b * HW;
#pragma unroll
  for (int c = 0; c < 3; ++c) {
    float xv = x[((size_t)b * 3 + c) * HW + hw];
    float uv = u[((size_t)b * 3 + c) * HW + hw];
    float ax = fabsf(xv);
    float sg = (xv > 0.0f) ? 1.0f : ((xv < 0.0f) ? -1.0f : 0.0f);
    float s  = (uv <= ax) ? sg : 0.0f;
    spk[(size_t)i * 32 + c] = __float2bfloat16(s);
  }
}

// Implicit-GEMM conv3x3(pad==dil) + BN + LIF.  MFMA 16x16x32 bf16, hi+lo weight split.
// Wave tile (M*16 px) x (N*16 co); block = 4 waves px-stacked.
// TRIPLE-buffered group pipeline: during body(g) we issue stage(g+2) (weights ->
// LDS buf (g+2)%3 via global_load_lds) and prefA(g+1) (A -> regs). At body(g) top:
//   s_waitcnt vmcnt(INSTS+AM): younger ops are exactly stage(g+1)+prefA(g) ->
//   in-order retirement guarantees stage(g) landed, ~2 groups after issue.
//   s_barrier + sched_barrier(0) (pins stage below the barrier: dbuf safety).
// OOB conv taps read a zeroed page (address select per tap, no per-chunk cndmask).
template<int M, int N, int GRP>
__global__ __launch_bounds__(256) void gemm_lif(
    const __hip_bfloat16* __restrict__ actin,
    const __hip_bfloat16* __restrict__ wsp,      // [2][Co][Kpad] hi, lo
    const float* __restrict__ bnt,               // [3][Co] for this timestep
    float* __restrict__ mem, __hip_bfloat16* __restrict__ actout,
    const __hip_bfloat16* __restrict__ zp,       // zero page (>= Cip+32 bf16, zeroed)
    int Cip, int Co, int lgHW, int lgW, int dil, int lgGX) {
  constexpr int NW = 4;
  constexpr int R  = N * 32;                 // LDS rows per chunk (hi+lo halves)
  constexpr int lgR = (N == 1) ? 5 : ((N == 2) ? 6 : 7);
  constexpr int BUFROWS = GRP * R;
  constexpr int BUFELEM = BUFROWS * 32;      // bf16 elems per buffer
  constexpr int INSTS = BUFROWS / (16 * NW); // global_load_lds per wave per group
  constexpr int AM = M * GRP;                // A-prefetch vm ops per group
  constexpr int WAITN = INSTS + AM;          // counted wait at group top
  __shared__ __hip_bfloat16 lds[3 * BUFELEM];

  const int HW = 1 << lgHW, H = HW >> lgW, W = 1 << lgW;
  const int Kpad = 9 * Cip;
  const unsigned CoKpad = (unsigned)Co * Kpad;
  const int lane = threadIdx.x & 63, wid = threadIdx.x >> 6;
  const int l15 = lane & 15, g = lane >> 4;

  // XCD-chunked bijective block swizzle (gridDim.x % 8 == 0)
  const int nb = gridDim.x;
  const int flat = blockIdx.x;
  const int swz = (flat & 7) * (nb >> 3) + (flat >> 3);
  const int bx = swz & ((1 << lgGX) - 1);
  const int by = swz >> lgGX;
  const int p0  = (bx * NW + wid) * (M * 16);
  const int co0 = by * (N * 16);

  // per-m-frag pixel decompose (16 consecutive px stay in one image row)
  int b_[M], y_[M], x_[M];
#pragma unroll
  for (int m = 0; m < M; ++m) {
    int pb = p0 + m * 16;
    b_[m] = pb >> lgHW;
    int rem = pb & (HW - 1);
    y_[m] = rem >> lgW;
    x_[m] = (rem & (W - 1)) + l15;
  }

  // weight staging source addrs (LDS dest linear; swizzle on GLOBAL source:
  // LDS slot s of row co holds global slot s ^ ((co>>1)&3))
  unsigned sgb[INSTS];
#pragma unroll
  for (int i = 0; i < INSTS; ++i) {
    int f  = wid * (BUFROWS / NW) + i * 16 + (lane >> 2);  // flat row in group
    int cc = f >> lgR;                // chunk within group
    int r  = f & (R - 1);             // row within chunk
    int half = r >> (lgR - 1);        // 0 = hi, 1 = lo  (16N rows each)
    int co   = r & (16 * N - 1);
    int slot = (lane & 3) ^ ((co >> 1) & 3);
    sgb[i] = (unsigned)half * CoKpad + (unsigned)(co0 + co) * Kpad + slot * 8 + cc * 32;
  }

  auto stage = [&](int grp, int buf) {
#pragma unroll
    for (int i = 0; i < INSTS; ++i) {
      const __hip_bfloat16* gp = wsp + sgb[i] + grp * (GRP * 32);
      __hip_bfloat16* lp = &lds[buf * BUFELEM + (wid * (BUFROWS / NW) + i * 16) * 32];
      __builtin_amdgcn_global_load_lds(
          (const __attribute__((address_space(1))) void*)gp,
          (__attribute__((address_space(3))) void*)lp, 16, 0, 0);
    }
  };

  const int cpt = Cip >> 5;            // chunks per tap (power of 2)
  const int lgcpt = __builtin_ctz(cpt);
  const int NGRP = (9 * cpt) / GRP;

  // rolling per-tap A addressing; OOB -> zero page (no per-chunk select needed)
  const __hip_bfloat16* apc[M];
  auto mkaddr = [&](int tap) {
    int ty = (tap * 11) >> 5;          // tap/3 for 0..8
    int tx = tap - ty * 3;
    int dy = (ty - 1) * dil, dx = (tx - 1) * dil;
#pragma unroll
    for (int m = 0; m < M; ++m) {
      int sy = y_[m] + dy, sx = x_[m] + dx;
      bool v = (sy >= 0) & (sy < H) & (sx >= 0) & (sx < W);
      int pix = (b_[m] << lgHW) + (sy << lgW) + sx;
      apc[m] = v ? (actin + (size_t)pix * Cip + 8 * g) : (zp + 8 * g);
    }
  };

  auto prefA = [&](int grp, short8v (&dst)[GRP][M]) {
#pragma unroll
    for (int cc = 0; cc < GRP; ++cc) {
      int c = grp * GRP + cc;
      if ((c & (cpt - 1)) == 0) mkaddr(c >> lgcpt);   // wave-uniform
      int kc = (c & (cpt - 1)) << 5;
#pragma unroll
      for (int m = 0; m < M; ++m)
        dst[cc][m] = *(const short8v*)(apc[m] + kc);
    }
  };

  f32x4 acc[M][N] = {};
  const int rdb = l15 * 32 + ((g ^ ((l15 >> 1) & 3)) * 8);  // swizzled read base

  short8v aA[GRP][M], aB[GRP][M];

  // one pipeline group: counted wait (stage(gi) landed), barrier, issue
  // stage(gi+2) + prefA(gi+1), then ds_read + MFMA on aU from lds[bc].
  auto grp_body = [&](int gi, int bc, short8v (&aU)[GRP][M], short8v (&aF)[GRP][M]) {
    asm volatile("s_waitcnt vmcnt(%0)" :: "n"(WAITN) : "memory");
    __builtin_amdgcn_s_barrier();
    __builtin_amdgcn_sched_barrier(0);

    if (gi + 2 < NGRP) {
      int b2 = bc + 2; if (b2 >= 3) b2 -= 3;
      stage(gi + 2, b2);
    }
    if (gi + 1 < NGRP) prefA(gi + 1, aF);

    const __hip_bfloat16* bp = &lds[bc * BUFELEM];
#pragma unroll
    for (int cc = 0; cc < GRP; ++cc) {
      short8v bh[N], bl[N];
#pragma unroll
      for (int j = 0; j < N; ++j) {
        bh[j] = *(const short8v*)(bp + cc * (R * 32) + j * 512 + rdb);
        bl[j] = *(const short8v*)(bp + cc * (R * 32) + (N * 512) + j * 512 + rdb);
      }
      __builtin_amdgcn_s_setprio(1);
#pragma unroll
      for (int j = 0; j < N; ++j)
#pragma unroll
        for (int m = 0; m < M; ++m) {
          acc[m][j] = __builtin_amdgcn_mfma_f32_16x16x32_bf16(aU[cc][m], bh[j], acc[m][j], 0, 0, 0);
          acc[m][j] = __builtin_amdgcn_mfma_f32_16x16x32_bf16(aU[cc][m], bl[j], acc[m][j], 0, 0, 0);
        }
      __builtin_amdgcn_s_setprio(0);
    }
  };

  // prologue: stage groups 0,1 ; prefetch A for group 0
  stage(0, 0);
  stage(1, 1);
  prefA(0, aA);

  int gi = 0, bc = 0;
  while (gi < NGRP) {
    grp_body(gi, bc, aA, aB); ++gi; bc = (bc == 2) ? 0 : bc + 1;
    if (gi < NGRP) { grp_body(gi, bc, aB, aA); ++gi; bc = (bc == 2) ? 0 : bc + 1; }
  }

  // epilogue: BN + LIF.  D: co = co0 + j*16 + l15, pixel = p0 + m*16 + 4g + r
#pragma unroll
  for (int j = 0; j < N; ++j) {
    int c = co0 + j * 16 + l15;
    float ga = bnt[c], mu = bnt[Co + c], va = bnt[2 * Co + c];
    float sc = ga / sqrtf(va + BNEPS);
#pragma unroll
    for (int m = 0; m < M; ++m) {
      int pixb = p0 + m * 16 + 4 * g;
#pragma unroll
      for (int r = 0; r < 4; ++r) {
        size_t idx = (size_t)(pixb + r) * Co + c;
        float bno = (acc[m][j][r] - mu) * sc;
        float mv = LEAK * mem[idx] + bno;
        float s = (mv > THRS) ? 1.0f : 0.0f;
        actout[idx] = __float2bfloat16(s);
        mem[idx] = mv - s;
      }
    }
  }
}

// AvgPool(3,2,1) storing SUM (exact ints in bf16); /9 folded into next layer weights.
// channel-last, vectorized: one thread = 8 channels of one output pixel.
__global__ void avgpool_sum8(const __hip_bfloat16* __restrict__ in,
                             __hip_bfloat16* __restrict__ out, int C, int H, int W) {
  const int Ho = H >> 1, Wo = W >> 1;
  const int C8 = C >> 3;
  const int n = BB * Ho * Wo * C8;
  int i = blockIdx.x * 256 + threadIdx.x;
  if (i >= n) return;
  int c8 = i % C8; int t = i / C8;
  int xo = t % Wo; t /= Wo;
  int yo = t % Ho; int b = t / Ho;
  const int y0 = 2 * yo - 1, x0 = 2 * xo - 1;
  float s[8] = {0, 0, 0, 0, 0, 0, 0, 0};
#pragma unroll
  for (int dy = 0; dy < 3; ++dy) {
    int iy = y0 + dy;
    if (iy < 0 || iy >= H) continue;
#pragma unroll
    for (int dx = 0; dx < 3; ++dx) {
      int ix = x0 + dx;
      if (ix < 0 || ix >= W) continue;
      short8v v = *(const short8v*)(in + (((size_t)b * H + iy) * W + ix) * C + c8 * 8);
#pragma unroll
      for (int e = 0; e < 8; ++e) {
        __hip_bfloat16_raw raw; raw.x = (unsigned short)v[e];
        s[e] += __bfloat162float(__hip_bfloat16(raw));
      }
    }
  }
  short8v o;
#pragma unroll
  for (int e = 0; e < 8; ++e) {
    __hip_bfloat16_raw raw = __hip_bfloat16_raw(__float2bfloat16(s[e]));
    o[e] = (short)raw.x;
  }
  *(short8v*)(out + (size_t)i * 8) = o;
}

// 1x1 conv 1024->21 @32x32, f32, accumulate into d_out. One wave per (b,pix).
__global__ void out_conv(const __hip_bfloat16* __restrict__ act,  // [B*1024px][1024ch]
                         const float* __restrict__ W8, float* __restrict__ out) {
  int gw = (blockIdx.x * 256 + threadIdx.x) >> 6;  // b*1024 + pix
  int lane = threadIdx.x & 63;
  int b = gw >> 10, pix = gw & 1023;
  const __hip_bfloat16* ap = act + ((size_t)gw << 10);
  float acc[NCLS];
#pragma unroll
  for (int c = 0; c < NCLS; ++c) acc[c] = 0.0f;
  for (int j = 0; j < 16; ++j) {
    int ci = j * 64 + lane;
    float av = __bfloat162float(ap[ci]);
#pragma unroll
    for (int c = 0; c < NCLS; ++c) acc[c] = fmaf(av, W8[c * 1024 + ci], acc[c]);
  }
#pragma unroll
  for (int c = 0; c < NCLS; ++c) {
    float v = acc[c];
    for (int off = 32; off; off >>= 1) v += __shfl_xor(v, off, 64);
    if (lane == 0) out[((size_t)b * NCLS + c) * 1024 + pix] += v;
  }
}

extern "C" void kernel_launch(void* const* d_in, const int* in_sizes, int n_in,
                              void* d_out, int out_size, void* d_ws, size_t ws_size,
                              hipStream_t stream) {
  const float* x = (const float*)d_in[0];
  const float* u = (const float*)d_in[1];
  const float* Wc[9];
  for (int i = 0; i < 9; ++i) Wc[i] = (const float*)d_in[2 + i];
  const float* bn[8];
  for (int i = 0; i < 8; ++i) bn[i] = (const float*)d_in[11 + i];

  const int Ci_[8]  = {3, 64, 64, 128, 128, 256, 256, 256};
  const int Cip_[8] = {32, 64, 64, 128, 128, 256, 256, 256};
  const int Co_[8]  = {64, 64, 128, 128, 256, 256, 256, 1024};
  const int HH_[8]  = {128, 128, 64, 64, 32, 32, 32, 32};
  const float wsc_[8] = {1.f, 1.f, 1.f / 9.f, 1.f, 1.f / 9.f, 1.f, 1.f, 1.f};

  float* ws = (float*)d_ws;
  size_t off = 0;
  auto align8 = [](size_t v) { return (v + 7) & ~(size_t)7; };

  float* memp[8];
  for (int i = 0; i < 8; ++i) {
    memp[i] = ws + off;
    off += (size_t)BB * HH_[i] * HH_[i] * Co_[i];
  }
  __hip_bfloat16* spk = (__hip_bfloat16*)(ws + off);
  off += (size_t)BB * 16384 * 32 / 2;
  __hip_bfloat16* zp = (__hip_bfloat16*)(ws + off);   // zero page (1 KB)
  off += 256;
  const size_t zero_floats = off;                     // mem + spk + zp zeroed each call
  __hip_bfloat16* actA = (__hip_bfloat16*)(ws + off); off += 2097152;
  __hip_bfloat16* actB = (__hip_bfloat16*)(ws + off); off += 2097152;
  __hip_bfloat16* wall[8];
  for (int i = 0; i < 8; ++i) {
    size_t n = (size_t)Co_[i] * 9 * Cip_[i];            // per half
    wall[i] = (__hip_bfloat16*)(ws + off);
    off = align8(off + n);                              // hi + lo = n floats
  }

  zero_f32<<<2048, 256, 0, stream>>>(ws, (int)zero_floats);
  zero_f32<<<(BB * NCLS * 1024 + 255) / 256, 256, 0, stream>>>((float*)d_out, BB * NCLS * 1024);

  for (int i = 0; i < 8; ++i) {
    int n = Co_[i] * 9 * Cip_[i];
    wsplit<<<(n + 255) / 256, 256, 0, stream>>>(Wc[i], wall[i], wall[i] + n,
                                                Co_[i], Ci_[i], Cip_[i], wsc_[i]);
  }

  const size_t uT = (size_t)BB * 3 * 16384;
  for (int t = 0; t < TT; ++t) {
    spike_gen<<<(BB * 16384 + 255) / 256, 256, 0, stream>>>(x, u + (size_t)t * uT, spk);
    // L0: 3(32)->64 @128   wave 32x64, block 128px x 64co, grid 512
    gemm_lif<2, 4, 3><<<512, 256, 0, stream>>>(spk,  wall[0], bn[0] + (size_t)t * 3 * 64,   memp[0], actA, zp, 32,  64,   14, 7, 1, 9);
    // L1: 64->64 @128
    gemm_lif<2, 4, 3><<<512, 256, 0, stream>>>(actA, wall[1], bn[1] + (size_t)t * 3 * 64,   memp[1], actB, zp, 64,  64,   14, 7, 1, 9);
    avgpool_sum8<<<(BB * 64 * 64 * 8 + 255) / 256, 256, 0, stream>>>(actB, actA, 64, 128, 128);
    // L2: 64->128 @64 (weights pre-scaled 1/9)  wave 32x32, grid 128x4
    gemm_lif<2, 2, 3><<<512, 256, 0, stream>>>(actA, wall[2], bn[2] + (size_t)t * 3 * 128,  memp[2], actB, zp, 64,  128,  12, 6, 1, 7);
    // L3: 128->128 @64
    gemm_lif<2, 2, 4><<<512, 256, 0, stream>>>(actB, wall[3], bn[3] + (size_t)t * 3 * 128,  memp[3], actA, zp, 128, 128,  12, 6, 1, 7);
    avgpool_sum8<<<(BB * 32 * 32 * 16 + 255) / 256, 256, 0, stream>>>(actA, actB, 128, 64, 64);
    // L4: 128->256 @32 (weights pre-scaled 1/9)  wave 16x32, grid 64x8
    gemm_lif<1, 2, 4><<<512, 256, 0, stream>>>(actB, wall[4], bn[4] + (size_t)t * 3 * 256,   memp[4], actA, zp, 128, 256,  10, 5, 1, 6);
    // L5: 256->256 @32 dil2
    gemm_lif<1, 2, 6><<<512, 256, 0, stream>>>(actA, wall[5], bn[5] + (size_t)t * 3 * 256,   memp[5], actB, zp, 256, 256,  10, 5, 2, 6);
    // L6: 256->256 @32 dil2
    gemm_lif<1, 2, 6><<<512, 256, 0, stream>>>(actB, wall[6], bn[6] + (size_t)t * 3 * 256,   memp[6], actA, zp, 256, 256,  10, 5, 2, 6);
    // L7: 256->1024 @32 dil12  wave 32x64, grid 32x16
    gemm_lif<2, 4, 3><<<512, 256, 0, stream>>>(actA, wall[7], bn[7] + (size_t)t * 3 * 1024, memp[7], actB, zp, 256, 1024, 10, 5, 12, 5);
    // output layer accumulation
    out_conv<<<dim3(BB * 1024 / 4), 256, 0, stream>>>(actB, Wc[8], (float*)d_out);
  }
  scale_f32<<<(BB * NCLS * 1024 + 255) / 256, 256, 0, stream>>>((float*)d_out, BB * NCLS * 1024, 1.0f / TT);
}

// Round 10
// 2058.163 us; speedup vs baseline: 1.1748x; 1.0057x over previous
//
#include <hip/hip_runtime.h>
#include <hip/hip_bf16.h>
#include <cstddef>
#include <cstdint>

#define LEAK  0.99f
#define THRS  1.0f
#define BNEPS 1e-4f

static constexpr int TT   = 8;
static constexpr int BB   = 4;
static constexpr int NCLS = 21;

typedef __attribute__((ext_vector_type(8))) short short8v;   // 8 bf16 (MFMA A/B frag)
typedef __attribute__((ext_vector_type(4))) float f32x4;     // MFMA C/D frag

__global__ void zero_f32(float* __restrict__ p, int n) {
  int i = blockIdx.x * blockDim.x + threadIdx.x;
  int stride = gridDim.x * blockDim.x;
  for (; i < n; i += stride) p[i] = 0.0f;
}

__global__ void scale_f32(float* __restrict__ p, int n, float s) {
  int i = blockIdx.x * blockDim.x + threadIdx.x;
  if (i < n) p[i] *= s;
}

// Split f32 weights (scaled) into hi+lo bf16, reordered to k = tap*Cip + ci.
__global__ void wsplit(const float* __restrict__ Wsrc,
                       __hip_bfloat16* __restrict__ whi, __hip_bfloat16* __restrict__ wlo,
                       int Co, int Ci, int Cip, float scale) {
  const int Kpad = 9 * Cip;
  const int n = Co * Kpad;
  int i = blockIdx.x * 256 + threadIdx.x;
  if (i >= n) return;
  int co = i / Kpad, k = i - co * Kpad;
  int tap = k / Cip, ci = k - tap * Cip;
  float w = 0.0f;
  if (ci < Ci) w = Wsrc[((size_t)co * Ci + ci) * 9 + tap] * scale;
  __hip_bfloat16 h = __float2bfloat16(w);
  float r = w - __bfloat162float(h);
  whi[i] = h;
  wlo[i] = __float2bfloat16(r);
}

// Poisson generator, writes channel-last [B][HW][32] (ch 3..31 pre-zeroed each call)
__global__ void spike_gen(const float* __restrict__ x, const float* __restrict__ u,
                          __hip_bfloat16* __restrict__ spk) {
  const int HW = 128 * 128;
  int i = blockIdx.x * 256 + threadIdx.x;  // b*HW + hw
  if (i >= BB * HW) return;
  int b = i / HW, hw = i - b * HW;
#pragma unroll
  for (int c = 0; c < 3; ++c) {
    float xv = x[((size_t)b * 3 + c) * HW + hw];
    float uv = u[((size_t)b * 3 + c) * HW + hw];
    float ax = fabsf(xv);
    float sg = (xv > 0.0f) ? 1.0f : ((xv < 0.0f) ? -1.0f : 0.0f);
    float s  = (uv <= ax) ? sg : 0.0f;
    spk[(size_t)i * 32 + c] = __float2bfloat16(s);
  }
}

// Implicit-GEMM conv3x3(pad==dil) + BN + LIF.  MFMA 16x16x32 bf16, hi+lo weight split.
// Wave tile (M*16 px) x (N*16 co); block = 4 waves px-stacked.
// TRIPLE-buffered, fully-unrolled group pipeline. Per body(g):
//   s_waitcnt vmcnt(INSTS+AM)  -> stage(g) retired (issued TWO groups ago)
//   s_barrier ; sched_barrier(0)
//   prefA(g+1)                 -> A regs; FIRST in vm queue (order-pinned)
//   sched_barrier(0)
//   stage(g+2)                 -> weights -> LDS buf (g+2)%3
//   ds_read + MFMA on buf g%3 using aU (prefA(g))
// vm queue: ..., prefA(g), stage(g+1), prefA(g+1), stage(g+2), ... so the
// compiler's pre-MFMA wait for prefA(g) does NOT drag stage(g+1) (in-order
// retirement) -> next-group weight fetch genuinely overlaps this group's MFMAs.
template<int M, int N, int GRP, int CPT>
__global__ __launch_bounds__(256) void gemm_lif(
    const __hip_bfloat16* __restrict__ actin,
    const __hip_bfloat16* __restrict__ wsp,      // [2][Co][Kpad] hi, lo
    const float* __restrict__ bnt,               // [3][Co] for this timestep
    float* __restrict__ mem, __hip_bfloat16* __restrict__ actout,
    const __hip_bfloat16* __restrict__ zp,       // zero page (>= Cip+32 bf16, zeroed)
    int Co, int lgHW, int lgW, int dil, int lgGX) {
  constexpr int NW = 4;
  constexpr int Cip = CPT * 32;
  constexpr int Kpad = 9 * Cip;
  constexpr int lgcpt = (CPT == 1) ? 0 : (CPT == 2) ? 1 : (CPT == 4) ? 2 : 3;
  constexpr int R  = N * 32;                 // LDS rows per chunk (hi+lo halves)
  constexpr int lgR = (N == 1) ? 5 : ((N == 2) ? 6 : 7);
  constexpr int BUFROWS = GRP * R;
  constexpr int BUFELEM = BUFROWS * 32;      // bf16 elems per buffer
  constexpr int INSTS = BUFROWS / (16 * NW); // global_load_lds per wave per group
  constexpr int AM = M * GRP;                // A-prefetch vm ops per group
  constexpr int WAITN = INSTS + AM;          // counted wait at group top
  constexpr int NGRP = (9 * CPT) / GRP;
  static_assert((9 * CPT) % GRP == 0, "group must divide chunk count");
  __shared__ __hip_bfloat16 lds[3 * BUFELEM];

  const int HW = 1 << lgHW, H = HW >> lgW, W = 1 << lgW;
  const unsigned CoKpad = (unsigned)Co * Kpad;
  const int lane = threadIdx.x & 63, wid = threadIdx.x >> 6;
  const int l15 = lane & 15, g = lane >> 4;

  // XCD-chunked bijective block swizzle (gridDim.x % 8 == 0)
  const int nb = gridDim.x;
  const int flat = blockIdx.x;
  const int swz = (flat & 7) * (nb >> 3) + (flat >> 3);
  const int bx = swz & ((1 << lgGX) - 1);
  const int by = swz >> lgGX;
  const int p0  = (bx * NW + wid) * (M * 16);
  const int co0 = by * (N * 16);

  // per-m-frag pixel decompose (16 consecutive px stay in one image row)
  int b_[M], y_[M], x_[M];
#pragma unroll
  for (int m = 0; m < M; ++m) {
    int pb = p0 + m * 16;
    b_[m] = pb >> lgHW;
    int rem = pb & (HW - 1);
    y_[m] = rem >> lgW;
    x_[m] = (rem & (W - 1)) + l15;
  }

  // weight staging source addrs (LDS dest linear; swizzle on GLOBAL source:
  // LDS slot s of row co holds global slot s ^ ((co>>1)&3))
  unsigned sgb[INSTS];
#pragma unroll
  for (int i = 0; i < INSTS; ++i) {
    int f  = wid * (BUFROWS / NW) + i * 16 + (lane >> 2);  // flat row in group
    int cc = f >> lgR;                // chunk within group
    int r  = f & (R - 1);             // row within chunk
    int half = r >> (lgR - 1);        // 0 = hi, 1 = lo  (16N rows each)
    int co   = r & (16 * N - 1);
    int slot = (lane & 3) ^ ((co >> 1) & 3);
    sgb[i] = (unsigned)half * CoKpad + (unsigned)(co0 + co) * Kpad + slot * 8 + cc * 32;
  }

  auto stage = [&](int grp, int buf) {
#pragma unroll
    for (int i = 0; i < INSTS; ++i) {
      const __hip_bfloat16* gp = wsp + sgb[i] + grp * (GRP * 32);
      __hip_bfloat16* lp = &lds[buf * BUFELEM + (wid * (BUFROWS / NW) + i * 16) * 32];
      __builtin_amdgcn_global_load_lds(
          (const __attribute__((address_space(1))) void*)gp,
          (__attribute__((address_space(3))) void*)lp, 16, 0, 0);
    }
  };

  // rolling per-tap A addressing; OOB -> zero page (no per-chunk select needed)
  const __hip_bfloat16* apc[M];
  auto mkaddr = [&](int tap) {
    int ty = (tap * 11) >> 5;          // tap/3 for 0..8
    int tx = tap - ty * 3;
    int dy = (ty - 1) * dil, dx = (tx - 1) * dil;
#pragma unroll
    for (int m = 0; m < M; ++m) {
      int sy = y_[m] + dy, sx = x_[m] + dx;
      bool v = (sy >= 0) & (sy < H) & (sx >= 0) & (sx < W);
      int pix = (b_[m] << lgHW) + (sy << lgW) + sx;
      apc[m] = v ? (actin + (size_t)pix * Cip + 8 * g) : (zp + 8 * g);
    }
  };

  auto prefA = [&](int grp, short8v (&dst)[GRP][M]) {
#pragma unroll
    for (int cc = 0; cc < GRP; ++cc) {
      int c = grp * GRP + cc;
      if ((c & (CPT - 1)) == 0) mkaddr(c >> lgcpt);   // wave-uniform
      int kc = (c & (CPT - 1)) << 5;
#pragma unroll
      for (int m = 0; m < M; ++m)
        dst[cc][m] = *(const short8v*)(apc[m] + kc);
    }
  };

  f32x4 acc[M][N] = {};
  const int rdb = l15 * 32 + ((g ^ ((l15 >> 1) & 3)) * 8);  // swizzled read base

  short8v aA[GRP][M], aB[GRP][M];

  auto grp_body = [&](int gi, int bc, short8v (&aU)[GRP][M], short8v (&aF)[GRP][M]) {
    asm volatile("s_waitcnt vmcnt(%0)" :: "n"(WAITN) : "memory");
    __builtin_amdgcn_s_barrier();
    __builtin_amdgcn_sched_barrier(0);

    if (gi + 1 < NGRP) prefA(gi + 1, aF);     // A-loads FIRST in vm queue
    __builtin_amdgcn_sched_barrier(0);        // pin order: prefA < stage
    if (gi + 2 < NGRP) {
      int b2 = bc + 2; if (b2 >= 3) b2 -= 3;
      stage(gi + 2, b2);
    }

    const __hip_bfloat16* bp = &lds[bc * BUFELEM];
#pragma unroll
    for (int cc = 0; cc < GRP; ++cc) {
      short8v bh[N], bl[N];
#pragma unroll
      for (int j = 0; j < N; ++j) {
        bh[j] = *(const short8v*)(bp + cc * (R * 32) + j * 512 + rdb);
        bl[j] = *(const short8v*)(bp + cc * (R * 32) + (N * 512) + j * 512 + rdb);
      }
      __builtin_amdgcn_s_setprio(1);
#pragma unroll
      for (int j = 0; j < N; ++j)
#pragma unroll
        for (int m = 0; m < M; ++m) {
          acc[m][j] = __builtin_amdgcn_mfma_f32_16x16x32_bf16(aU[cc][m], bh[j], acc[m][j], 0, 0, 0);
          acc[m][j] = __builtin_amdgcn_mfma_f32_16x16x32_bf16(aU[cc][m], bl[j], acc[m][j], 0, 0, 0);
        }
      __builtin_amdgcn_s_setprio(0);
    }
  };

  // prologue (order-pinned): stage(0) ; prefA(0) ; stage(1)
  stage(0, 0);
  __builtin_amdgcn_sched_barrier(0);
  prefA(0, aA);
  __builtin_amdgcn_sched_barrier(0);
  if (NGRP > 1) stage(1, 1);

#pragma unroll
  for (int gi = 0; gi < NGRP; ++gi) {
    const int bc = gi % 3;
    if (gi & 1) grp_body(gi, bc, aB, aA);
    else        grp_body(gi, bc, aA, aB);
  }

  // epilogue: BN + LIF.  D: co = co0 + j*16 + l15, pixel = p0 + m*16 + 4g + r
#pragma unroll
  for (int j = 0; j < N; ++j) {
    int c = co0 + j * 16 + l15;
    float ga = bnt[c], mu = bnt[Co + c], va = bnt[2 * Co + c];
    float sc = ga / sqrtf(va + BNEPS);
#pragma unroll
    for (int m = 0; m < M; ++m) {
      int pixb = p0 + m * 16 + 4 * g;
#pragma unroll
      for (int r = 0; r < 4; ++r) {
        size_t idx = (size_t)(pixb + r) * Co + c;
        float bno = (acc[m][j][r] - mu) * sc;
        float mv = LEAK * mem[idx] + bno;
        float s = (mv > THRS) ? 1.0f : 0.0f;
        actout[idx] = __float2bfloat16(s);
        mem[idx] = mv - s;
      }
    }
  }
}

// AvgPool(3,2,1) storing SUM (exact ints in bf16); /9 folded into next layer weights.
__global__ void avgpool_sum8(const __hip_bfloat16* __restrict__ in,
                             __hip_bfloat16* __restrict__ out, int C, int H, int W) {
  const int Ho = H >> 1, Wo = W >> 1;
  const int C8 = C >> 3;
  const int n = BB * Ho * Wo * C8;
  int i = blockIdx.x * 256 + threadIdx.x;
  if (i >= n) return;
  int c8 = i % C8; int t = i / C8;
  int xo = t % Wo; t /= Wo;
  int yo = t % Ho; int b = t / Ho;
  const int y0 = 2 * yo - 1, x0 = 2 * xo - 1;
  float s[8] = {0, 0, 0, 0, 0, 0, 0, 0};
#pragma unroll
  for (int dy = 0; dy < 3; ++dy) {
    int iy = y0 + dy;
    if (iy < 0 || iy >= H) continue;
#pragma unroll
    for (int dx = 0; dx < 3; ++dx) {
      int ix = x0 + dx;
      if (ix < 0 || ix >= W) continue;
      short8v v = *(const short8v*)(in + (((size_t)b * H + iy) * W + ix) * C + c8 * 8);
#pragma unroll
      for (int e = 0; e < 8; ++e) {
        __hip_bfloat16_raw raw; raw.x = (unsigned short)v[e];
        s[e] += __bfloat162float(__hip_bfloat16(raw));
      }
    }
  }
  short8v o;
#pragma unroll
  for (int e = 0; e < 8; ++e) {
    __hip_bfloat16_raw raw = __hip_bfloat16_raw(__float2bfloat16(s[e]));
    o[e] = (short)raw.x;
  }
  *(short8v*)(out + (size_t)i * 8) = o;
}

// 1x1 conv 1024->21 @32x32, f32, accumulate into d_out. One wave per (b,pix).
__global__ void out_conv(const __hip_bfloat16* __restrict__ act,  // [B*1024px][1024ch]
                         const float* __restrict__ W8, float* __restrict__ out) {
  int gw = (blockIdx.x * 256 + threadIdx.x) >> 6;  // b*1024 + pix
  int lane = threadIdx.x & 63;
  int b = gw >> 10, pix = gw & 1023;
  const __hip_bfloat16* ap = act + ((size_t)gw << 10);
  float acc[NCLS];
#pragma unroll
  for (int c = 0; c < NCLS; ++c) acc[c] = 0.0f;
  for (int j = 0; j < 16; ++j) {
    int ci = j * 64 + lane;
    float av = __bfloat162float(ap[ci]);
#pragma unroll
    for (int c = 0; c < NCLS; ++c) acc[c] = fmaf(av, W8[c * 1024 + ci], acc[c]);
  }
#pragma unroll
  for (int c = 0; c < NCLS; ++c) {
    float v = acc[c];
    for (int off = 32; off; off >>= 1) v += __shfl_xor(v, off, 64);
    if (lane == 0) out[((size_t)b * NCLS + c) * 1024 + pix] += v;
  }
}

extern "C" void kernel_launch(void* const* d_in, const int* in_sizes, int n_in,
                              void* d_out, int out_size, void* d_ws, size_t ws_size,
                              hipStream_t stream) {
  const float* x = (const float*)d_in[0];
  const float* u = (const float*)d_in[1];
  const float* Wc[9];
  for (int i = 0; i < 9; ++i) Wc[i] = (const float*)d_in[2 + i];
  const float* bn[8];
  for (int i = 0; i < 8; ++i) bn[i] = (const float*)d_in[11 + i];

  const int Ci_[8]  = {3, 64, 64, 128, 128, 256, 256, 256};
  const int Cip_[8] = {32, 64, 64, 128, 128, 256, 256, 256};
  const int Co_[8]  = {64, 64, 128, 128, 256, 256, 256, 1024};
  const int HH_[8]  = {128, 128, 64, 64, 32, 32, 32, 32};
  const float wsc_[8] = {1.f, 1.f, 1.f / 9.f, 1.f, 1.f / 9.f, 1.f, 1.f, 1.f};

  float* ws = (float*)d_ws;
  size_t off = 0;
  auto align8 = [](size_t v) { return (v + 7) & ~(size_t)7; };

  float* memp[8];
  for (int i = 0; i < 8; ++i) {
    memp[i] = ws + off;
    off += (size_t)BB * HH_[i] * HH_[i] * Co_[i];
  }
  __hip_bfloat16* spk = (__hip_bfloat16*)(ws + off);
  off += (size_t)BB * 16384 * 32 / 2;
  __hip_bfloat16* zp = (__hip_bfloat16*)(ws + off);   // zero page (1 KB)
  off += 256;
  const size_t zero_floats = off;                     // mem + spk + zp zeroed each call
  __hip_bfloat16* actA = (__hip_bfloat16*)(ws + off); off += 2097152;
  __hip_bfloat16* actB = (__hip_bfloat16*)(ws + off); off += 2097152;
  __hip_bfloat16* wall[8];
  for (int i = 0; i < 8; ++i) {
    size_t n = (size_t)Co_[i] * 9 * Cip_[i];            // per half
    wall[i] = (__hip_bfloat16*)(ws + off);
    off = align8(off + n);                              // hi + lo = n floats
  }

  zero_f32<<<2048, 256, 0, stream>>>(ws, (int)zero_floats);
  zero_f32<<<(BB * NCLS * 1024 + 255) / 256, 256, 0, stream>>>((float*)d_out, BB * NCLS * 1024);

  for (int i = 0; i < 8; ++i) {
    int n = Co_[i] * 9 * Cip_[i];
    wsplit<<<(n + 255) / 256, 256, 0, stream>>>(Wc[i], wall[i], wall[i] + n,
                                                Co_[i], Ci_[i], Cip_[i], wsc_[i]);
  }

  const size_t uT = (size_t)BB * 3 * 16384;
  for (int t = 0; t < TT; ++t) {
    spike_gen<<<(BB * 16384 + 255) / 256, 256, 0, stream>>>(x, u + (size_t)t * uT, spk);
    // L0: 3(32)->64 @128   wave 32x64, grid 512
    gemm_lif<2, 4, 3, 1><<<512, 256, 0, stream>>>(spk,  wall[0], bn[0] + (size_t)t * 3 * 64,   memp[0], actA, zp, 64,   14, 7, 1, 9);
    // L1: 64->64 @128
    gemm_lif<2, 4, 3, 2><<<512, 256, 0, stream>>>(actA, wall[1], bn[1] + (size_t)t * 3 * 64,   memp[1], actB, zp, 64,   14, 7, 1, 9);
    avgpool_sum8<<<(BB * 64 * 64 * 8 + 255) / 256, 256, 0, stream>>>(actB, actA, 64, 128, 128);
    // L2: 64->128 @64 (weights pre-scaled 1/9)  wave 32x32, grid 128x4
    gemm_lif<2, 2, 3, 2><<<512, 256, 0, stream>>>(actA, wall[2], bn[2] + (size_t)t * 3 * 128,  memp[2], actB, zp, 128,  12, 6, 1, 7);
    // L3: 128->128 @64
    gemm_lif<2, 2, 4, 4><<<512, 256, 0, stream>>>(actB, wall[3], bn[3] + (size_t)t * 3 * 128,  memp[3], actA, zp, 128,  12, 6, 1, 7);
    avgpool_sum8<<<(BB * 32 * 32 * 16 + 255) / 256, 256, 0, stream>>>(actA, actB, 128, 64, 64);
    // L4: 128->256 @32 (weights pre-scaled 1/9)  wave 16x32, grid 64x8
    gemm_lif<1, 2, 4, 4><<<512, 256, 0, stream>>>(actB, wall[4], bn[4] + (size_t)t * 3 * 256,   memp[4], actA, zp, 256,  10, 5, 1, 6);
    // L5: 256->256 @32 dil2
    gemm_lif<1, 2, 6, 8><<<512, 256, 0, stream>>>(actA, wall[5], bn[5] + (size_t)t * 3 * 256,   memp[5], actB, zp, 256,  10, 5, 2, 6);
    // L6: 256->256 @32 dil2
    gemm_lif<1, 2, 6, 8><<<512, 256, 0, stream>>>(actB, wall[6], bn[6] + (size_t)t * 3 * 256,   memp[6], actA, zp, 256,  10, 5, 2, 6);
    // L7: 256->1024 @32 dil12  wave 32x64, grid 32x16
    gemm_lif<2, 4, 3, 8><<<512, 256, 0, stream>>>(actA, wall[7], bn[7] + (size_t)t * 3 * 1024, memp[7], actB, zp, 1024, 10, 5, 12, 5);
    // output layer accumulation
    out_conv<<<dim3(BB * 1024 / 4), 256, 0, stream>>>(actB, Wc[8], (float*)d_out);
  }
  scale_f32<<<(BB * NCLS * 1024 + 255) / 256, 256, 0, stream>>>((float*)d_out, BB * NCLS * 1024, 1.0f / TT);
}

// Round 11
// 2020.358 us; speedup vs baseline: 1.1968x; 1.0187x over previous
//
#include <hip/hip_runtime.h>
#include <hip/hip_bf16.h>
#include <cstddef>
#include <cstdint>

#define LEAK  0.99f
#define THRS  1.0f
#define BNEPS 1e-4f

static constexpr int TT   = 8;
static constexpr int BB   = 4;
static constexpr int NCLS = 21;

typedef __attribute__((ext_vector_type(8))) short short8v;   // 8 bf16 (MFMA A/B frag)
typedef __attribute__((ext_vector_type(4))) float f32x4;     // MFMA C/D frag

__global__ void zero_f32(float* __restrict__ p, int n) {
  int i = blockIdx.x * blockDim.x + threadIdx.x;
  int stride = gridDim.x * blockDim.x;
  for (; i < n; i += stride) p[i] = 0.0f;
}

__global__ void scale_f32(float* __restrict__ p, int n, float s) {
  int i = blockIdx.x * blockDim.x + threadIdx.x;
  if (i < n) p[i] *= s;
}

// Split f32 weights (scaled) into hi+lo bf16, reordered to k = tap*Cip + ci.
__global__ void wsplit(const float* __restrict__ Wsrc,
                       __hip_bfloat16* __restrict__ whi, __hip_bfloat16* __restrict__ wlo,
                       int Co, int Ci, int Cip, float scale) {
  const int Kpad = 9 * Cip;
  const int n = Co * Kpad;
  int i = blockIdx.x * 256 + threadIdx.x;
  if (i >= n) return;
  int co = i / Kpad, k = i - co * Kpad;
  int tap = k / Cip, ci = k - tap * Cip;
  float w = 0.0f;
  if (ci < Ci) w = Wsrc[((size_t)co * Ci + ci) * 9 + tap] * scale;
  __hip_bfloat16 h = __float2bfloat16(w);
  float r = w - __bfloat162float(h);
  whi[i] = h;
  wlo[i] = __float2bfloat16(r);
}

// Poisson generator, writes channel-last [B][HW][32] (ch 3..31 pre-zeroed each call)
__global__ void spike_gen(const float* __restrict__ x, const float* __restrict__ u,
                          __hip_bfloat16* __restrict__ spk) {
  const int HW = 128 * 128;
  int i = blockIdx.x * 256 + threadIdx.x;  // b*HW + hw
  if (i >= BB * HW) return;
  int b = i / HW, hw = i - b * HW;
#pragma unroll
  for (int c = 0; c < 3; ++c) {
    float xv = x[((size_t)b * 3 + c) * HW + hw];
    float uv = u[((size_t)b * 3 + c) * HW + hw];
    float ax = fabsf(xv);
    float sg = (xv > 0.0f) ? 1.0f : ((xv < 0.0f) ? -1.0f : 0.0f);
    float s  = (uv <= ax) ? sg : 0.0f;
    spk[(size_t)i * 32 + c] = __float2bfloat16(s);
  }
}

// Implicit-GEMM conv3x3(pad==dil) + BN + LIF.  MFMA 16x16x32 bf16, hi+lo weight split.
// Wave tile (M*16 px) x (N*16 co). Block = 4 px-waves x SPLIT k-halves.
// Per k-half: r7 double-buffered counted-vmcnt group pipeline:
//   top of body(g): s_waitcnt vmcnt(AM) -> stage(g) (issued one group ago) retired,
//   s_barrier + sched_barrier(0); then stage(g+1)+prefA(g+1); ds_read; MFMA.
// SPLIT=2: waves 0-3 accumulate chunks [0,NCH), waves 4-7 chunks [NCH,2*NCH);
// partials merged through LDS (reusing staging buffers after the loop); epilogue
// runs on half 0. 2x the waves per layer -> 4 waves/SIMD (latency overlap).
template<int M, int N, int GRP, int CPT, int SPLIT>
__global__ __launch_bounds__(SPLIT * 256, 4) void gemm_lif(
    const __hip_bfloat16* __restrict__ actin,
    const __hip_bfloat16* __restrict__ wsp,      // [2][Co][Kpad] hi, lo
    const float* __restrict__ bnt,               // [3][Co] for this timestep
    float* __restrict__ mem, __hip_bfloat16* __restrict__ actout,
    const __hip_bfloat16* __restrict__ zp,       // zero page (>= Cip bf16, zeroed)
    int Co, int lgHW, int lgW, int dil, int lgGX) {
  constexpr int NW = 4;                      // px-waves per (half-)block
  constexpr int Cip = CPT * 32;
  constexpr int Kpad = 9 * Cip;
  constexpr int lgcpt = (CPT == 1) ? 0 : (CPT == 2) ? 1 : (CPT == 4) ? 2 : 3;
  constexpr int R  = N * 32;                 // LDS rows per chunk (hi+lo halves)
  constexpr int lgR = (N == 1) ? 5 : ((N == 2) ? 6 : 7);
  constexpr int BUFROWS = GRP * R;
  constexpr int BUFELEM = BUFROWS * 32;      // bf16 elems per buffer
  constexpr int INSTS = BUFROWS / (16 * NW); // global_load_lds per wave per group
  constexpr int AM = M * GRP;                // A-prefetch vm ops per group
  constexpr int WAITN = AM;                  // counted wait at group top (r7)
  constexpr int NCH = (9 * CPT) / SPLIT;     // chunks per k-half
  constexpr int NGRP = NCH / GRP;
  static_assert(NCH % GRP == 0, "group must divide per-half chunk count");
  __shared__ __hip_bfloat16 lds[SPLIT * 2 * BUFELEM];

  const int HW = 1 << lgHW, H = HW >> lgW, W = 1 << lgW;
  const unsigned CoKpad = (unsigned)Co * Kpad;
  const int lane = threadIdx.x & 63, wid = threadIdx.x >> 6;
  const int kw = wid >> 2;                   // k-half (0 for SPLIT=1)
  const int wq = wid & 3;                    // px position within block
  const int l15 = lane & 15, g = lane >> 4;
  __hip_bfloat16* ldsh = lds + kw * 2 * BUFELEM;

  // XCD-chunked bijective block swizzle (gridDim.x % 8 == 0)
  const int nb = gridDim.x;
  const int flat = blockIdx.x;
  const int swz = (flat & 7) * (nb >> 3) + (flat >> 3);
  const int bx = swz & ((1 << lgGX) - 1);
  const int by = swz >> lgGX;
  const int p0  = (bx * NW + wq) * (M * 16);
  const int co0 = by * (N * 16);

  // per-m-frag pixel decompose (16 consecutive px stay in one image row)
  int b_[M], y_[M], x_[M];
#pragma unroll
  for (int m = 0; m < M; ++m) {
    int pb = p0 + m * 16;
    b_[m] = pb >> lgHW;
    int rem = pb & (HW - 1);
    y_[m] = rem >> lgW;
    x_[m] = (rem & (W - 1)) + l15;
  }

  // weight staging source addrs (LDS dest linear; swizzle on GLOBAL source:
  // LDS slot s of row co holds global slot s ^ ((co>>1)&3)). kbase selects k-half.
  const unsigned kbase = (unsigned)kw * (NCH * 32);
  unsigned sgb[INSTS];
#pragma unroll
  for (int i = 0; i < INSTS; ++i) {
    int f  = wq * (BUFROWS / NW) + i * 16 + (lane >> 2);  // flat row in group buf
    int cc = f >> lgR;                // chunk within group
    int r  = f & (R - 1);             // row within chunk
    int half = r >> (lgR - 1);        // 0 = hi, 1 = lo  (16N rows each)
    int co   = r & (16 * N - 1);
    int slot = (lane & 3) ^ ((co >> 1) & 3);
    sgb[i] = (unsigned)half * CoKpad + (unsigned)(co0 + co) * Kpad + slot * 8
           + cc * 32 + kbase;
  }

  auto stage = [&](int gl, int buf) {      // gl = local group index in this half
#pragma unroll
    for (int i = 0; i < INSTS; ++i) {
      const __hip_bfloat16* gp = wsp + sgb[i] + gl * (GRP * 32);
      __hip_bfloat16* lp = &ldsh[buf * BUFELEM + (wq * (BUFROWS / NW) + i * 16) * 32];
      __builtin_amdgcn_global_load_lds(
          (const __attribute__((address_space(1))) void*)gp,
          (__attribute__((address_space(3))) void*)lp, 16, 0, 0);
    }
  };

  // rolling per-tap A addressing; OOB -> zero page
  const __hip_bfloat16* apc[M];
  auto mkaddr = [&](int tap) {
    int ty = (tap * 11) >> 5;          // tap/3 for 0..8
    int tx = tap - ty * 3;
    int dy = (ty - 1) * dil, dx = (tx - 1) * dil;
#pragma unroll
    for (int m = 0; m < M; ++m) {
      int sy = y_[m] + dy, sx = x_[m] + dx;
      bool v = (sy >= 0) & (sy < H) & (sx >= 0) & (sx < W);
      int pix = (b_[m] << lgHW) + (sy << lgW) + sx;
      apc[m] = v ? (actin + (size_t)pix * Cip + 8 * g) : (zp + 8 * g);
    }
  };

  auto prefA = [&](int gl, short8v (&dst)[GRP][M], bool first) {
#pragma unroll
    for (int cc = 0; cc < GRP; ++cc) {
      int c = kw * NCH + gl * GRP + cc;                 // global chunk index
      if ((c & (CPT - 1)) == 0 || (first && cc == 0)) mkaddr(c >> lgcpt);
      int kc = (c & (CPT - 1)) << 5;
#pragma unroll
      for (int m = 0; m < M; ++m)
        dst[cc][m] = *(const short8v*)(apc[m] + kc);
    }
  };

  f32x4 acc[M][N] = {};
  const int rdb = l15 * 32 + ((g ^ ((l15 >> 1) & 3)) * 8);  // swizzled read base

  short8v aA[GRP][M], aB[GRP][M];

  auto grp_body = [&](int gi, short8v (&aU)[GRP][M], short8v (&aF)[GRP][M]) {
    asm volatile("s_waitcnt vmcnt(%0)" :: "n"(WAITN) : "memory");
    __builtin_amdgcn_s_barrier();
    __builtin_amdgcn_sched_barrier(0);

    if (gi + 1 < NGRP) {
      stage(gi + 1, (gi + 1) & 1);
      prefA(gi + 1, aF, false);
    }

    const __hip_bfloat16* bp = &ldsh[(gi & 1) * BUFELEM];
#pragma unroll
    for (int cc = 0; cc < GRP; ++cc) {
      short8v bh[N], bl[N];
#pragma unroll
      for (int j = 0; j < N; ++j) {
        bh[j] = *(const short8v*)(bp + cc * (R * 32) + j * 512 + rdb);
        bl[j] = *(const short8v*)(bp + cc * (R * 32) + (N * 512) + j * 512 + rdb);
      }
      __builtin_amdgcn_s_setprio(1);
#pragma unroll
      for (int j = 0; j < N; ++j)
#pragma unroll
        for (int m = 0; m < M; ++m) {
          acc[m][j] = __builtin_amdgcn_mfma_f32_16x16x32_bf16(aU[cc][m], bh[j], acc[m][j], 0, 0, 0);
          acc[m][j] = __builtin_amdgcn_mfma_f32_16x16x32_bf16(aU[cc][m], bl[j], acc[m][j], 0, 0, 0);
        }
      __builtin_amdgcn_s_setprio(0);
    }
  };

  // prologue: stage group 0 of my half, prefetch its A
  stage(0, 0);
  prefA(0, aA, true);

#pragma unroll
  for (int gi = 0; gi < NGRP; ++gi) {
    if (gi & 1) grp_body(gi, aB, aA);
    else        grp_body(gi, aA, aB);
  }

  // SPLIT=2: merge k-half partials through LDS (staging buffers are dead now)
  if constexpr (SPLIT == 2) {
    asm volatile("s_waitcnt vmcnt(0) lgkmcnt(0)" ::: "memory");
    __builtin_amdgcn_s_barrier();
    f32x4* red = (f32x4*)lds;
    const int rbase = (wq * 64 + lane) * (M * N);
    if (kw == 1) {
#pragma unroll
      for (int m = 0; m < M; ++m)
#pragma unroll
        for (int j = 0; j < N; ++j)
          red[rbase + m * N + j] = acc[m][j];
    }
    asm volatile("s_waitcnt lgkmcnt(0)" ::: "memory");
    __builtin_amdgcn_s_barrier();
    if (kw == 1) return;
#pragma unroll
    for (int m = 0; m < M; ++m)
#pragma unroll
      for (int j = 0; j < N; ++j) {
        f32x4 t = red[rbase + m * N + j];
#pragma unroll
        for (int r = 0; r < 4; ++r) acc[m][j][r] += t[r];
      }
  }

  // epilogue: BN + LIF.  D: co = co0 + j*16 + l15, pixel = p0 + m*16 + 4g + r
#pragma unroll
  for (int j = 0; j < N; ++j) {
    int c = co0 + j * 16 + l15;
    float ga = bnt[c], mu = bnt[Co + c], va = bnt[2 * Co + c];
    float sc = ga / sqrtf(va + BNEPS);
#pragma unroll
    for (int m = 0; m < M; ++m) {
      int pixb = p0 + m * 16 + 4 * g;
#pragma unroll
      for (int r = 0; r < 4; ++r) {
        size_t idx = (size_t)(pixb + r) * Co + c;
        float bno = (acc[m][j][r] - mu) * sc;
        float mv = LEAK * mem[idx] + bno;
        float s = (mv > THRS) ? 1.0f : 0.0f;
        actout[idx] = __float2bfloat16(s);
        mem[idx] = mv - s;
      }
    }
  }
}

// AvgPool(3,2,1) storing SUM (exact ints in bf16); /9 folded into next layer weights.
__global__ void avgpool_sum8(const __hip_bfloat16* __restrict__ in,
                             __hip_bfloat16* __restrict__ out, int C, int H, int W) {
  const int Ho = H >> 1, Wo = W >> 1;
  const int C8 = C >> 3;
  const int n = BB * Ho * Wo * C8;
  int i = blockIdx.x * 256 + threadIdx.x;
  if (i >= n) return;
  int c8 = i % C8; int t = i / C8;
  int xo = t % Wo; t /= Wo;
  int yo = t % Ho; int b = t / Ho;
  const int y0 = 2 * yo - 1, x0 = 2 * xo - 1;
  float s[8] = {0, 0, 0, 0, 0, 0, 0, 0};
#pragma unroll
  for (int dy = 0; dy < 3; ++dy) {
    int iy = y0 + dy;
    if (iy < 0 || iy >= H) continue;
#pragma unroll
    for (int dx = 0; dx < 3; ++dx) {
      int ix = x0 + dx;
      if (ix < 0 || ix >= W) continue;
      short8v v = *(const short8v*)(in + (((size_t)b * H + iy) * W + ix) * C + c8 * 8);
#pragma unroll
      for (int e = 0; e < 8; ++e) {
        __hip_bfloat16_raw raw; raw.x = (unsigned short)v[e];
        s[e] += __bfloat162float(__hip_bfloat16(raw));
      }
    }
  }
  short8v o;
#pragma unroll
  for (int e = 0; e < 8; ++e) {
    __hip_bfloat16_raw raw = __hip_bfloat16_raw(__float2bfloat16(s[e]));
    o[e] = (short)raw.x;
  }
  *(short8v*)(out + (size_t)i * 8) = o;
}

// 1x1 conv 1024->21 @32x32, f32, accumulate into d_out. One wave per (b,pix).
__global__ void out_conv(const __hip_bfloat16* __restrict__ act,  // [B*1024px][1024ch]
                         const float* __restrict__ W8, float* __restrict__ out) {
  int gw = (blockIdx.x * 256 + threadIdx.x) >> 6;  // b*1024 + pix
  int lane = threadIdx.x & 63;
  int b = gw >> 10, pix = gw & 1023;
  const __hip_bfloat16* ap = act + ((size_t)gw << 10);
  float acc[NCLS];
#pragma unroll
  for (int c = 0; c < NCLS; ++c) acc[c] = 0.0f;
  for (int j = 0; j < 16; ++j) {
    int ci = j * 64 + lane;
    float av = __bfloat162float(ap[ci]);
#pragma unroll
    for (int c = 0; c < NCLS; ++c) acc[c] = fmaf(av, W8[c * 1024 + ci], acc[c]);
  }
#pragma unroll
  for (int c = 0; c < NCLS; ++c) {
    float v = acc[c];
    for (int off = 32; off; off >>= 1) v += __shfl_xor(v, off, 64);
    if (lane == 0) out[((size_t)b * NCLS + c) * 1024 + pix] += v;
  }
}

extern "C" void kernel_launch(void* const* d_in, const int* in_sizes, int n_in,
                              void* d_out, int out_size, void* d_ws, size_t ws_size,
                              hipStream_t stream) {
  const float* x = (const float*)d_in[0];
  const float* u = (const float*)d_in[1];
  const float* Wc[9];
  for (int i = 0; i < 9; ++i) Wc[i] = (const float*)d_in[2 + i];
  const float* bn[8];
  for (int i = 0; i < 8; ++i) bn[i] = (const float*)d_in[11 + i];

  const int Ci_[8]  = {3, 64, 64, 128, 128, 256, 256, 256};
  const int Cip_[8] = {32, 64, 64, 128, 128, 256, 256, 256};
  const int Co_[8]  = {64, 64, 128, 128, 256, 256, 256, 1024};
  const int HH_[8]  = {128, 128, 64, 64, 32, 32, 32, 32};
  const float wsc_[8] = {1.f, 1.f, 1.f / 9.f, 1.f, 1.f / 9.f, 1.f, 1.f, 1.f};

  float* ws = (float*)d_ws;
  size_t off = 0;
  auto align8 = [](size_t v) { return (v + 7) & ~(size_t)7; };

  float* memp[8];
  for (int i = 0; i < 8; ++i) {
    memp[i] = ws + off;
    off += (size_t)BB * HH_[i] * HH_[i] * Co_[i];
  }
  __hip_bfloat16* spk = (__hip_bfloat16*)(ws + off);
  off += (size_t)BB * 16384 * 32 / 2;
  __hip_bfloat16* zp = (__hip_bfloat16*)(ws + off);   // zero page (1 KB)
  off += 256;
  const size_t zero_floats = off;                     // mem + spk + zp zeroed each call
  __hip_bfloat16* actA = (__hip_bfloat16*)(ws + off); off += 2097152;
  __hip_bfloat16* actB = (__hip_bfloat16*)(ws + off); off += 2097152;
  __hip_bfloat16* wall[8];
  for (int i = 0; i < 8; ++i) {
    size_t n = (size_t)Co_[i] * 9 * Cip_[i];            // per half
    wall[i] = (__hip_bfloat16*)(ws + off);
    off = align8(off + n);                              // hi + lo = n floats
  }

  zero_f32<<<2048, 256, 0, stream>>>(ws, (int)zero_floats);
  zero_f32<<<(BB * NCLS * 1024 + 255) / 256, 256, 0, stream>>>((float*)d_out, BB * NCLS * 1024);

  for (int i = 0; i < 8; ++i) {
    int n = Co_[i] * 9 * Cip_[i];
    wsplit<<<(n + 255) / 256, 256, 0, stream>>>(Wc[i], wall[i], wall[i] + n,
                                                Co_[i], Ci_[i], Cip_[i], wsc_[i]);
  }

  const size_t uT = (size_t)BB * 3 * 16384;
  for (int t = 0; t < TT; ++t) {
    spike_gen<<<(BB * 16384 + 255) / 256, 256, 0, stream>>>(x, u + (size_t)t * uT, spk);
    // L0: 3(32)->64 @128   wave 32x32, grid 1024 (4 blk/CU, 4 waves/SIMD)
    gemm_lif<2, 2, 3, 1, 1><<<1024, 256, 0, stream>>>(spk,  wall[0], bn[0] + (size_t)t * 3 * 64,   memp[0], actA, zp, 64,   14, 7, 1, 9);
    // L1: 64->64 @128      wave 32x32, grid 1024
    gemm_lif<2, 2, 3, 2, 1><<<1024, 256, 0, stream>>>(actA, wall[1], bn[1] + (size_t)t * 3 * 64,   memp[1], actB, zp, 64,   14, 7, 1, 9);
    avgpool_sum8<<<(BB * 64 * 64 * 8 + 255) / 256, 256, 0, stream>>>(actB, actA, 64, 128, 128);
    // L2: 64->128 @64 (w/9)  wave 32x32, split-K x2, 512 blk x 512 thr (4 w/SIMD)
    gemm_lif<2, 2, 3, 2, 2><<<512, 512, 0, stream>>>(actA, wall[2], bn[2] + (size_t)t * 3 * 128,  memp[2], actB, zp, 128,  12, 6, 1, 7);
    // L3: 128->128 @64       split-K x2
    gemm_lif<2, 2, 3, 4, 2><<<512, 512, 0, stream>>>(actB, wall[3], bn[3] + (size_t)t * 3 * 128,  memp[3], actA, zp, 128,  12, 6, 1, 7);
    avgpool_sum8<<<(BB * 32 * 32 * 16 + 255) / 256, 256, 0, stream>>>(actA, actB, 128, 64, 64);
    // L4: 128->256 @32 (w/9) wave 16x32, split-K x2
    gemm_lif<1, 2, 3, 4, 2><<<512, 512, 0, stream>>>(actB, wall[4], bn[4] + (size_t)t * 3 * 256,   memp[4], actA, zp, 256,  10, 5, 1, 6);
    // L5: 256->256 @32 dil2  split-K x2
    gemm_lif<1, 2, 4, 8, 2><<<512, 512, 0, stream>>>(actA, wall[5], bn[5] + (size_t)t * 3 * 256,   memp[5], actB, zp, 256,  10, 5, 2, 6);
    // L6: 256->256 @32 dil2  split-K x2
    gemm_lif<1, 2, 4, 8, 2><<<512, 512, 0, stream>>>(actB, wall[6], bn[6] + (size_t)t * 3 * 256,   memp[6], actA, zp, 256,  10, 5, 2, 6);
    // L7: 256->1024 @32 dil12  wave 32x64, split-K x2
    gemm_lif<2, 4, 2, 8, 2><<<512, 512, 0, stream>>>(actA, wall[7], bn[7] + (size_t)t * 3 * 1024, memp[7], actB, zp, 1024, 10, 5, 12, 5);
    // output layer accumulation
    out_conv<<<dim3(BB * 1024 / 4), 256, 0, stream>>>(actB, Wc[8], (float*)d_out);
  }
  scale_f32<<<(BB * NCLS * 1024 + 255) / 256, 256, 0, stream>>>((float*)d_out, BB * NCLS * 1024, 1.0f / TT);
}

// Round 12
// 1947.716 us; speedup vs baseline: 1.2414x; 1.0373x over previous
//
#include <hip/hip_runtime.h>
#include <hip/hip_bf16.h>
#include <cstddef>
#include <cstdint>

#define LEAK  0.99f
#define THRS  1.0f
#define BNEPS 1e-4f

static constexpr int TT   = 8;
static constexpr int BB   = 4;
static constexpr int NCLS = 21;

typedef __attribute__((ext_vector_type(8))) short short8v;   // 8 bf16 (MFMA A/B frag)
typedef __attribute__((ext_vector_type(4))) float f32x4;     // MFMA C/D frag

__global__ void zero_f32(float* __restrict__ p, int n) {
  int i = blockIdx.x * blockDim.x + threadIdx.x;
  int stride = gridDim.x * blockDim.x;
  for (; i < n; i += stride) p[i] = 0.0f;
}

__global__ void scale_f32(float* __restrict__ p, int n, float s) {
  int i = blockIdx.x * blockDim.x + threadIdx.x;
  if (i < n) p[i] *= s;
}

// Split f32 weights (scaled) into hi+lo bf16, reordered to k = tap*Cip + ci.
__global__ void wsplit(const float* __restrict__ Wsrc,
                       __hip_bfloat16* __restrict__ whi, __hip_bfloat16* __restrict__ wlo,
                       int Co, int Ci, int Cip, float scale) {
  const int Kpad = 9 * Cip;
  const int n = Co * Kpad;
  int i = blockIdx.x * 256 + threadIdx.x;
  if (i >= n) return;
  int co = i / Kpad, k = i - co * Kpad;
  int tap = k / Cip, ci = k - tap * Cip;
  float w = 0.0f;
  if (ci < Ci) w = Wsrc[((size_t)co * Ci + ci) * 9 + tap] * scale;
  __hip_bfloat16 h = __float2bfloat16(w);
  float r = w - __bfloat162float(h);
  whi[i] = h;
  wlo[i] = __float2bfloat16(r);
}

// Poisson generator, writes channel-last [B][HW][32] (ch 3..31 pre-zeroed each call)
__global__ void spike_gen(const float* __restrict__ x, const float* __restrict__ u,
                          __hip_bfloat16* __restrict__ spk) {
  const int HW = 128 * 128;
  int i = blockIdx.x * 256 + threadIdx.x;  // b*HW + hw
  if (i >= BB * HW) return;
  int b = i / HW, hw = i - b * HW;
#pragma unroll
  for (int c = 0; c < 3; ++c) {
    float xv = x[((size_t)b * 3 + c) * HW + hw];
    float uv = u[((size_t)b * 3 + c) * HW + hw];
    float ax = fabsf(xv);
    float sg = (xv > 0.0f) ? 1.0f : ((xv < 0.0f) ? -1.0f : 0.0f);
    float s  = (uv <= ax) ? sg : 0.0f;
    spk[(size_t)i * 32 + c] = __float2bfloat16(s);
  }
}

// Implicit-GEMM conv3x3(pad==dil) + BN + LIF.  MFMA 16x16x32 bf16, hi+lo weight split.
// Wave tile (M*16 px) x (N*16 co). Block = 4 px-waves x SPLIT k-halves.
// Group pipeline with FINE-GRAINED per-chunk interleave (m196/8-phase style):
//   top of body(g): s_waitcnt vmcnt(AM) -> stage(g) retired; s_barrier; sched_barrier.
//   stage(g+1) burst (global_load_lds: no VGPR writeback, keeps wait arithmetic).
//   Then PER CHUNK cc: {prefA-slice cc of group g+1 -> ds_read B(cc) ->
//   setprio(1) MFMA cluster setprio(0)} — A-load issue distributed between MFMA
//   clusters instead of bursting at group top.
// SPLIT=2: waves 0-3 chunks [0,NCH), waves 4-7 [NCH,2NCH); partials merged via
// LDS f32 planes (4B/lane stride -> bank-conflict-free); epilogue on half 0.
template<int M, int N, int GRP, int CPT, int SPLIT>
__global__ __launch_bounds__(SPLIT * 256, 4) void gemm_lif(
    const __hip_bfloat16* __restrict__ actin,
    const __hip_bfloat16* __restrict__ wsp,      // [2][Co][Kpad] hi, lo
    const float* __restrict__ bnt,               // [3][Co] for this timestep
    float* __restrict__ mem, __hip_bfloat16* __restrict__ actout,
    const __hip_bfloat16* __restrict__ zp,       // zero page (>= Cip bf16, zeroed)
    int Co, int lgHW, int lgW, int dil, int lgGX) {
  constexpr int NW = 4;                      // px-waves per (half-)block
  constexpr int Cip = CPT * 32;
  constexpr int Kpad = 9 * Cip;
  constexpr int lgcpt = (CPT == 1) ? 0 : (CPT == 2) ? 1 : (CPT == 4) ? 2 : 3;
  constexpr int R  = N * 32;                 // LDS rows per chunk (hi+lo halves)
  constexpr int lgR = (N == 1) ? 5 : ((N == 2) ? 6 : 7);
  constexpr int BUFROWS = GRP * R;
  constexpr int BUFELEM = BUFROWS * 32;      // bf16 elems per buffer
  constexpr int INSTS = BUFROWS / (16 * NW); // global_load_lds per wave per group
  constexpr int AM = M * GRP;                // A-prefetch vm ops per group
  constexpr int WAITN = AM;                  // counted wait at group top
  constexpr int NCH = (9 * CPT) / SPLIT;     // chunks per k-half
  constexpr int NGRP = NCH / GRP;
  static_assert(NCH % GRP == 0, "group must divide per-half chunk count");
  __shared__ __hip_bfloat16 lds[SPLIT * 2 * BUFELEM];

  const int HW = 1 << lgHW, H = HW >> lgW, W = 1 << lgW;
  const unsigned CoKpad = (unsigned)Co * Kpad;
  const int lane = threadIdx.x & 63, wid = threadIdx.x >> 6;
  const int kw = wid >> 2;                   // k-half (0 for SPLIT=1)
  const int wq = wid & 3;                    // px position within block
  const int l15 = lane & 15, g = lane >> 4;
  __hip_bfloat16* ldsh = lds + kw * 2 * BUFELEM;

  // XCD-chunked bijective block swizzle (gridDim.x % 8 == 0)
  const int nb = gridDim.x;
  const int flat = blockIdx.x;
  const int swz = (flat & 7) * (nb >> 3) + (flat >> 3);
  const int bx = swz & ((1 << lgGX) - 1);
  const int by = swz >> lgGX;
  const int p0  = (bx * NW + wq) * (M * 16);
  const int co0 = by * (N * 16);

  // per-m-frag pixel decompose (16 consecutive px stay in one image row)
  int b_[M], y_[M], x_[M];
#pragma unroll
  for (int m = 0; m < M; ++m) {
    int pb = p0 + m * 16;
    b_[m] = pb >> lgHW;
    int rem = pb & (HW - 1);
    y_[m] = rem >> lgW;
    x_[m] = (rem & (W - 1)) + l15;
  }

  // weight staging source addrs (LDS dest linear; swizzle on GLOBAL source:
  // LDS slot s of row co holds global slot s ^ ((co>>1)&3)). kbase selects k-half.
  const unsigned kbase = (unsigned)kw * (NCH * 32);
  unsigned sgb[INSTS];
#pragma unroll
  for (int i = 0; i < INSTS; ++i) {
    int f  = wq * (BUFROWS / NW) + i * 16 + (lane >> 2);  // flat row in group buf
    int cc = f >> lgR;                // chunk within group
    int r  = f & (R - 1);             // row within chunk
    int half = r >> (lgR - 1);        // 0 = hi, 1 = lo  (16N rows each)
    int co   = r & (16 * N - 1);
    int slot = (lane & 3) ^ ((co >> 1) & 3);
    sgb[i] = (unsigned)half * CoKpad + (unsigned)(co0 + co) * Kpad + slot * 8
           + cc * 32 + kbase;
  }

  auto stage = [&](int gl, int buf) {      // gl = local group index in this half
#pragma unroll
    for (int i = 0; i < INSTS; ++i) {
      const __hip_bfloat16* gp = wsp + sgb[i] + gl * (GRP * 32);
      __hip_bfloat16* lp = &ldsh[buf * BUFELEM + (wq * (BUFROWS / NW) + i * 16) * 32];
      __builtin_amdgcn_global_load_lds(
          (const __attribute__((address_space(1))) void*)gp,
          (__attribute__((address_space(3))) void*)lp, 16, 0, 0);
    }
  };

  // rolling per-tap A addressing; OOB -> zero page
  const __hip_bfloat16* apc[M];
  auto mkaddr = [&](int tap) {
    int ty = (tap * 11) >> 5;          // tap/3 for 0..8
    int tx = tap - ty * 3;
    int dy = (ty - 1) * dil, dx = (tx - 1) * dil;
#pragma unroll
    for (int m = 0; m < M; ++m) {
      int sy = y_[m] + dy, sx = x_[m] + dx;
      bool v = (sy >= 0) & (sy < H) & (sx >= 0) & (sx < W);
      int pix = (b_[m] << lgHW) + (sy << lgW) + sx;
      apc[m] = v ? (actin + (size_t)pix * Cip + 8 * g) : (zp + 8 * g);
    }
  };

  // A-prefetch slice: one chunk's M fragments (issued between MFMA clusters)
  auto prefA_slice = [&](int cg, int cc, short8v (&dst)[GRP][M], bool force) {
    if ((cg & (CPT - 1)) == 0 || force) mkaddr(cg >> lgcpt);   // wave-uniform
    int kc = (cg & (CPT - 1)) << 5;
#pragma unroll
    for (int m = 0; m < M; ++m)
      dst[cc][m] = *(const short8v*)(apc[m] + kc);
  };

  f32x4 acc[M][N] = {};
  const int rdb = l15 * 32 + ((g ^ ((l15 >> 1) & 3)) * 8);  // swizzled read base

  short8v aA[GRP][M], aB[GRP][M];

  auto grp_body = [&](int gi, short8v (&aU)[GRP][M], short8v (&aF)[GRP][M]) {
    asm volatile("s_waitcnt vmcnt(%0)" :: "n"(WAITN) : "memory");
    __builtin_amdgcn_s_barrier();
    __builtin_amdgcn_sched_barrier(0);

    const bool more = (gi + 1 < NGRP);
    if (more) stage(gi + 1, (gi + 1) & 1);   // no VGPR writeback; first in vm queue

    const __hip_bfloat16* bp = &ldsh[(gi & 1) * BUFELEM];
#pragma unroll
    for (int cc = 0; cc < GRP; ++cc) {
      if (more) prefA_slice(kw * NCH + (gi + 1) * GRP + cc, cc, aF, false);
      short8v bh[N], bl[N];
#pragma unroll
      for (int j = 0; j < N; ++j) {
        bh[j] = *(const short8v*)(bp + cc * (R * 32) + j * 512 + rdb);
        bl[j] = *(const short8v*)(bp + cc * (R * 32) + (N * 512) + j * 512 + rdb);
      }
      __builtin_amdgcn_s_setprio(1);
#pragma unroll
      for (int j = 0; j < N; ++j)
#pragma unroll
        for (int m = 0; m < M; ++m) {
          acc[m][j] = __builtin_amdgcn_mfma_f32_16x16x32_bf16(aU[cc][m], bh[j], acc[m][j], 0, 0, 0);
          acc[m][j] = __builtin_amdgcn_mfma_f32_16x16x32_bf16(aU[cc][m], bl[j], acc[m][j], 0, 0, 0);
        }
      __builtin_amdgcn_s_setprio(0);
    }
  };

  // prologue: stage group 0 of my half, prefetch its A (sliced)
  stage(0, 0);
#pragma unroll
  for (int cc = 0; cc < GRP; ++cc)
    prefA_slice(kw * NCH + cc, cc, aA, cc == 0);

#pragma unroll
  for (int gi = 0; gi < NGRP; ++gi) {
    if (gi & 1) grp_body(gi, aB, aA);
    else        grp_body(gi, aA, aB);
  }

  // SPLIT=2: merge k-half partials via LDS f32 planes (4B/lane -> conflict-free)
  if constexpr (SPLIT == 2) {
    asm volatile("s_waitcnt vmcnt(0) lgkmcnt(0)" ::: "memory");
    __builtin_amdgcn_s_barrier();
    float* red = (float*)lds;
    const int tid = wq * 64 + lane;
    if (kw == 1) {
#pragma unroll
      for (int m = 0; m < M; ++m)
#pragma unroll
        for (int j = 0; j < N; ++j)
#pragma unroll
          for (int r = 0; r < 4; ++r)
            red[((m * N + j) * 4 + r) * 256 + tid] = acc[m][j][r];
    }
    asm volatile("s_waitcnt lgkmcnt(0)" ::: "memory");
    __builtin_amdgcn_s_barrier();
    if (kw == 1) return;
#pragma unroll
    for (int m = 0; m < M; ++m)
#pragma unroll
      for (int j = 0; j < N; ++j)
#pragma unroll
        for (int r = 0; r < 4; ++r)
          acc[m][j][r] += red[((m * N + j) * 4 + r) * 256 + tid];
  }

  // epilogue: BN + LIF.  D: co = co0 + j*16 + l15, pixel = p0 + m*16 + 4g + r
#pragma unroll
  for (int j = 0; j < N; ++j) {
    int c = co0 + j * 16 + l15;
    float ga = bnt[c], mu = bnt[Co + c], va = bnt[2 * Co + c];
    float sc = ga / sqrtf(va + BNEPS);
#pragma unroll
    for (int m = 0; m < M; ++m) {
      int pixb = p0 + m * 16 + 4 * g;
#pragma unroll
      for (int r = 0; r < 4; ++r) {
        size_t idx = (size_t)(pixb + r) * Co + c;
        float bno = (acc[m][j][r] - mu) * sc;
        float mv = LEAK * mem[idx] + bno;
        float s = (mv > THRS) ? 1.0f : 0.0f;
        actout[idx] = __float2bfloat16(s);
        mem[idx] = mv - s;
      }
    }
  }
}

// AvgPool(3,2,1) storing SUM (exact ints in bf16); /9 folded into next layer weights.
__global__ void avgpool_sum8(const __hip_bfloat16* __restrict__ in,
                             __hip_bfloat16* __restrict__ out, int C, int H, int W) {
  const int Ho = H >> 1, Wo = W >> 1;
  const int C8 = C >> 3;
  const int n = BB * Ho * Wo * C8;
  int i = blockIdx.x * 256 + threadIdx.x;
  if (i >= n) return;
  int c8 = i % C8; int t = i / C8;
  int xo = t % Wo; t /= Wo;
  int yo = t % Ho; int b = t / Ho;
  const int y0 = 2 * yo - 1, x0 = 2 * xo - 1;
  float s[8] = {0, 0, 0, 0, 0, 0, 0, 0};
#pragma unroll
  for (int dy = 0; dy < 3; ++dy) {
    int iy = y0 + dy;
    if (iy < 0 || iy >= H) continue;
#pragma unroll
    for (int dx = 0; dx < 3; ++dx) {
      int ix = x0 + dx;
      if (ix < 0 || ix >= W) continue;
      short8v v = *(const short8v*)(in + (((size_t)b * H + iy) * W + ix) * C + c8 * 8);
#pragma unroll
      for (int e = 0; e < 8; ++e) {
        __hip_bfloat16_raw raw; raw.x = (unsigned short)v[e];
        s[e] += __bfloat162float(__hip_bfloat16(raw));
      }
    }
  }
  short8v o;
#pragma unroll
  for (int e = 0; e < 8; ++e) {
    __hip_bfloat16_raw raw = __hip_bfloat16_raw(__float2bfloat16(s[e]));
    o[e] = (short)raw.x;
  }
  *(short8v*)(out + (size_t)i * 8) = o;
}

// 1x1 conv 1024->21 @32x32, f32, accumulate into d_out. One wave per (b,pix).
__global__ void out_conv(const __hip_bfloat16* __restrict__ act,  // [B*1024px][1024ch]
                         const float* __restrict__ W8, float* __restrict__ out) {
  int gw = (blockIdx.x * 256 + threadIdx.x) >> 6;  // b*1024 + pix
  int lane = threadIdx.x & 63;
  int b = gw >> 10, pix = gw & 1023;
  const __hip_bfloat16* ap = act + ((size_t)gw << 10);
  float acc[NCLS];
#pragma unroll
  for (int c = 0; c < NCLS; ++c) acc[c] = 0.0f;
  for (int j = 0; j < 16; ++j) {
    int ci = j * 64 + lane;
    float av = __bfloat162float(ap[ci]);
#pragma unroll
    for (int c = 0; c < NCLS; ++c) acc[c] = fmaf(av, W8[c * 1024 + ci], acc[c]);
  }
#pragma unroll
  for (int c = 0; c < NCLS; ++c) {
    float v = acc[c];
    for (int off = 32; off; off >>= 1) v += __shfl_xor(v, off, 64);
    if (lane == 0) out[((size_t)b * NCLS + c) * 1024 + pix] += v;
  }
}

extern "C" void kernel_launch(void* const* d_in, const int* in_sizes, int n_in,
                              void* d_out, int out_size, void* d_ws, size_t ws_size,
                              hipStream_t stream) {
  const float* x = (const float*)d_in[0];
  const float* u = (const float*)d_in[1];
  const float* Wc[9];
  for (int i = 0; i < 9; ++i) Wc[i] = (const float*)d_in[2 + i];
  const float* bn[8];
  for (int i = 0; i < 8; ++i) bn[i] = (const float*)d_in[11 + i];

  const int Ci_[8]  = {3, 64, 64, 128, 128, 256, 256, 256};
  const int Cip_[8] = {32, 64, 64, 128, 128, 256, 256, 256};
  const int Co_[8]  = {64, 64, 128, 128, 256, 256, 256, 1024};
  const int HH_[8]  = {128, 128, 64, 64, 32, 32, 32, 32};
  const float wsc_[8] = {1.f, 1.f, 1.f / 9.f, 1.f, 1.f / 9.f, 1.f, 1.f, 1.f};

  float* ws = (float*)d_ws;
  size_t off = 0;
  auto align8 = [](size_t v) { return (v + 7) & ~(size_t)7; };

  float* memp[8];
  for (int i = 0; i < 8; ++i) {
    memp[i] = ws + off;
    off += (size_t)BB * HH_[i] * HH_[i] * Co_[i];
  }
  __hip_bfloat16* spk = (__hip_bfloat16*)(ws + off);
  off += (size_t)BB * 16384 * 32 / 2;
  __hip_bfloat16* zp = (__hip_bfloat16*)(ws + off);   // zero page (1 KB)
  off += 256;
  const size_t zero_floats = off;                     // mem + spk + zp zeroed each call
  __hip_bfloat16* actA = (__hip_bfloat16*)(ws + off); off += 2097152;
  __hip_bfloat16* actB = (__hip_bfloat16*)(ws + off); off += 2097152;
  __hip_bfloat16* wall[8];
  for (int i = 0; i < 8; ++i) {
    size_t n = (size_t)Co_[i] * 9 * Cip_[i];            // per half
    wall[i] = (__hip_bfloat16*)(ws + off);
    off = align8(off + n);                              // hi + lo = n floats
  }

  zero_f32<<<2048, 256, 0, stream>>>(ws, (int)zero_floats);
  zero_f32<<<(BB * NCLS * 1024 + 255) / 256, 256, 0, stream>>>((float*)d_out, BB * NCLS * 1024);

  for (int i = 0; i < 8; ++i) {
    int n = Co_[i] * 9 * Cip_[i];
    wsplit<<<(n + 255) / 256, 256, 0, stream>>>(Wc[i], wall[i], wall[i] + n,
                                                Co_[i], Ci_[i], Cip_[i], wsc_[i]);
  }

  const size_t uT = (size_t)BB * 3 * 16384;
  for (int t = 0; t < TT; ++t) {
    spike_gen<<<(BB * 16384 + 255) / 256, 256, 0, stream>>>(x, u + (size_t)t * uT, spk);
    // L0: 3(32)->64 @128   wave 32x32, grid 1024 (4 blk/CU, 4 waves/SIMD)
    gemm_lif<2, 2, 3, 1, 1><<<1024, 256, 0, stream>>>(spk,  wall[0], bn[0] + (size_t)t * 3 * 64,   memp[0], actA, zp, 64,   14, 7, 1, 9);
    // L1: 64->64 @128      wave 32x32, grid 1024
    gemm_lif<2, 2, 3, 2, 1><<<1024, 256, 0, stream>>>(actA, wall[1], bn[1] + (size_t)t * 3 * 64,   memp[1], actB, zp, 64,   14, 7, 1, 9);
    avgpool_sum8<<<(BB * 64 * 64 * 8 + 255) / 256, 256, 0, stream>>>(actB, actA, 64, 128, 128);
    // L2: 64->128 @64 (w/9)  wave 32x32, split-K x2, 512 blk x 512 thr (4 w/SIMD)
    gemm_lif<2, 2, 3, 2, 2><<<512, 512, 0, stream>>>(actA, wall[2], bn[2] + (size_t)t * 3 * 128,  memp[2], actB, zp, 128,  12, 6, 1, 7);
    // L3: 128->128 @64       split-K x2
    gemm_lif<2, 2, 3, 4, 2><<<512, 512, 0, stream>>>(actB, wall[3], bn[3] + (size_t)t * 3 * 128,  memp[3], actA, zp, 128,  12, 6, 1, 7);
    avgpool_sum8<<<(BB * 32 * 32 * 16 + 255) / 256, 256, 0, stream>>>(actA, actB, 128, 64, 64);
    // L4: 128->256 @32 (w/9) wave 16x32, split-K x2
    gemm_lif<1, 2, 3, 4, 2><<<512, 512, 0, stream>>>(actB, wall[4], bn[4] + (size_t)t * 3 * 256,   memp[4], actA, zp, 256,  10, 5, 1, 6);
    // L5: 256->256 @32 dil2  split-K x2
    gemm_lif<1, 2, 4, 8, 2><<<512, 512, 0, stream>>>(actA, wall[5], bn[5] + (size_t)t * 3 * 256,   memp[5], actB, zp, 256,  10, 5, 2, 6);
    // L6: 256->256 @32 dil2  split-K x2
    gemm_lif<1, 2, 4, 8, 2><<<512, 512, 0, stream>>>(actB, wall[6], bn[6] + (size_t)t * 3 * 256,   memp[6], actA, zp, 256,  10, 5, 2, 6);
    // L7: 256->1024 @32 dil12  wave 32x64, split-K x2
    gemm_lif<2, 4, 2, 8, 2><<<512, 512, 0, stream>>>(actA, wall[7], bn[7] + (size_t)t * 3 * 1024, memp[7], actB, zp, 1024, 10, 5, 12, 5);
    // output layer accumulation
    out_conv<<<dim3(BB * 1024 / 4), 256, 0, stream>>>(actB, Wc[8], (float*)d_out);
  }
  scale_f32<<<(BB * NCLS * 1024 + 255) / 256, 256, 0, stream>>>((float*)d_out, BB * NCLS * 1024, 1.0f / TT);
}

// Round 13
// 1908.252 us; speedup vs baseline: 1.2671x; 1.0207x over previous
//
#include <hip/hip_runtime.h>
#include <hip/hip_bf16.h>
#include <cstddef>
#include <cstdint>

#define LEAK  0.99f
#define THRS  1.0f
#define BNEPS 1e-4f

static constexpr int TT   = 8;
static constexpr int BB   = 4;
static constexpr int NCLS = 21;

typedef __attribute__((ext_vector_type(8))) short short8v;   // 8 bf16 (MFMA A/B frag)
typedef __attribute__((ext_vector_type(4))) float f32x4;     // MFMA C/D frag

__global__ void zero_f32(float* __restrict__ p, int n) {
  int i = blockIdx.x * blockDim.x + threadIdx.x;
  int stride = gridDim.x * blockDim.x;
  for (; i < n; i += stride) p[i] = 0.0f;
}

__global__ void scale_f32(float* __restrict__ p, int n, float s) {
  int i = blockIdx.x * blockDim.x + threadIdx.x;
  if (i < n) p[i] *= s;
}

// Split f32 weights (scaled) into hi+lo bf16, reordered to k = tap*Cip + ci.
__global__ void wsplit(const float* __restrict__ Wsrc,
                       __hip_bfloat16* __restrict__ whi, __hip_bfloat16* __restrict__ wlo,
                       int Co, int Ci, int Cip, float scale) {
  const int Kpad = 9 * Cip;
  const int n = Co * Kpad;
  int i = blockIdx.x * 256 + threadIdx.x;
  if (i >= n) return;
  int co = i / Kpad, k = i - co * Kpad;
  int tap = k / Cip, ci = k - tap * Cip;
  float w = 0.0f;
  if (ci < Ci) w = Wsrc[((size_t)co * Ci + ci) * 9 + tap] * scale;
  __hip_bfloat16 h = __float2bfloat16(w);
  float r = w - __bfloat162float(h);
  whi[i] = h;
  wlo[i] = __float2bfloat16(r);
}

// L0 packed weights: k = slot*8 + ci, 12 slots (9 taps + 3 zero), 8ch (3 real).
__global__ void wsplit_l0(const float* __restrict__ W0,
                          __hip_bfloat16* __restrict__ whi, __hip_bfloat16* __restrict__ wlo) {
  int i = blockIdx.x * 256 + threadIdx.x;      // co*96 + k
  if (i >= 64 * 96) return;
  int co = i / 96, k = i - co * 96;
  int slot = k >> 3, ci = k & 7;
  float w = 0.0f;
  if (slot < 9 && ci < 3) w = W0[((size_t)co * 3 + ci) * 9 + slot];
  __hip_bfloat16 h = __float2bfloat16(w);
  float r = w - __bfloat162float(h);
  whi[i] = h;
  wlo[i] = __float2bfloat16(r);
}

// Poisson generator -> channel-last [B*HW][8] (ch 3..7 zero), one 16B store/px.
__global__ void spike_gen8(const float* __restrict__ x, const float* __restrict__ u,
                           __hip_bfloat16* __restrict__ spk) {
  const int HW = 128 * 128;
  int i = blockIdx.x * 256 + threadIdx.x;  // b*HW + hw
  if (i >= BB * HW) return;
  int b = i / HW, hw = i - b * HW;
  short8v o = {};
#pragma unroll
  for (int c = 0; c < 3; ++c) {
    float xv = x[((size_t)b * 3 + c) * HW + hw];
    float uv = u[((size_t)b * 3 + c) * HW + hw];
    float ax = fabsf(xv);
    float sg = (xv > 0.0f) ? 1.0f : ((xv < 0.0f) ? -1.0f : 0.0f);
    float s  = (uv <= ax) ? sg : 0.0f;
    __hip_bfloat16_raw raw = __hip_bfloat16_raw(__float2bfloat16(s));
    o[c] = (short)raw.x;
  }
  *(short8v*)(spk + (size_t)i * 8) = o;
}

// L0 dedicated: tap-packed implicit GEMM. K = 96 (12 slots x 8ch), 3 chunks.
// Wave tile 32px x 32co, block 4 waves (128px x 32co), grid 512x2 = 1024.
// Per lane, k-group g = tap within chunk -> per-lane pixel addressing; OOB or
// pad slots read the zero page (weights there are 0 anyway).
__global__ __launch_bounds__(256) void gemm_lif_l0(
    const __hip_bfloat16* __restrict__ spk,   // [B*HW][8]
    const __hip_bfloat16* __restrict__ wsp,   // [2][64][96] hi, lo
    const float* __restrict__ bnt, float* __restrict__ mem,
    __hip_bfloat16* __restrict__ actout,
    const __hip_bfloat16* __restrict__ zp) {
  constexpr int M = 2, Co = 64, Kpk = 96, HW = 16384, H = 128, W = 128;
  __shared__ __hip_bfloat16 lds[3 * 64 * 32];     // 3 chunks x 64 rows x 32 (12 KB)
  const int lane = threadIdx.x & 63, wid = threadIdx.x >> 6;
  const int l15 = lane & 15, g = lane >> 4;

  const int nb = gridDim.x;                        // 1024
  const int flat = blockIdx.x;
  const int swz = (flat & 7) * (nb >> 3) + (flat >> 3);
  const int bx = swz & 511, by = swz >> 9;
  const int p0 = (bx * 4 + wid) * 32;
  const int co0 = by * 32;

  int b_[M], y_[M], x_[M];
#pragma unroll
  for (int m = 0; m < M; ++m) {
    int pb = p0 + m * 16;
    b_[m] = pb >> 14;
    int rem = pb & (HW - 1);
    y_[m] = rem >> 7;
    x_[m] = (rem & 127) + l15;
  }

  // stage all 3 chunks (192 rows of 32): 3 insts/wave; swizzled global source
  unsigned sgb[3];
#pragma unroll
  for (int i = 0; i < 3; ++i) {
    int f = wid * 48 + i * 16 + (lane >> 2);
    int cc = f >> 6;            // chunk
    int r  = f & 63;
    int half = r >> 5;          // 0 hi, 1 lo
    int co   = r & 31;
    int slot = (lane & 3) ^ ((co >> 1) & 3);
    sgb[i] = (unsigned)half * Co * Kpk + (unsigned)(co0 + co) * Kpk + slot * 8 + cc * 32;
  }
#pragma unroll
  for (int i = 0; i < 3; ++i) {
    const __hip_bfloat16* gp = wsp + sgb[i];
    __hip_bfloat16* lp = &lds[(wid * 48 + i * 16) * 32];
    __builtin_amdgcn_global_load_lds(
        (const __attribute__((address_space(1))) void*)gp,
        (__attribute__((address_space(3))) void*)lp, 16, 0, 0);
  }

  // A: 3 chunks x M frags; per-lane tap = chunk*4 + g
  short8v aA[3][M];
#pragma unroll
  for (int c = 0; c < 3; ++c) {
    int tap = c * 4 + g;
    int ty = (tap * 11) >> 5;        // tap/3 (tap<=11: 11*11>>5=3 ok for 9..11 but masked below)
    int tx = tap - ty * 3;
    int dy = ty - 1, dx = tx - 1;
#pragma unroll
    for (int m = 0; m < M; ++m) {
      int sy = y_[m] + dy, sx = x_[m] + dx;
      bool v = (tap < 9) & (sy >= 0) & (sy < H) & (sx >= 0) & (sx < W);
      int pix = (b_[m] << 14) + (sy << 7) + sx;
      const __hip_bfloat16* ap = v ? (spk + (size_t)pix * 8) : zp;
      aA[c][m] = *(const short8v*)ap;
    }
  }

  asm volatile("s_waitcnt vmcnt(%0)" :: "n"(6) : "memory");  // 3 stage retired; 6 A in flight
  __builtin_amdgcn_s_barrier();
  __builtin_amdgcn_sched_barrier(0);

  f32x4 acc[M][2] = {};
  const int rdb = l15 * 32 + ((g ^ ((l15 >> 1) & 3)) * 8);
#pragma unroll
  for (int c = 0; c < 3; ++c) {
    short8v bh[2], bl[2];
#pragma unroll
    for (int j = 0; j < 2; ++j) {
      bh[j] = *(const short8v*)(&lds[c * 2048] + j * 512 + rdb);
      bl[j] = *(const short8v*)(&lds[c * 2048] + 1024 + j * 512 + rdb);
    }
    __builtin_amdgcn_s_setprio(1);
#pragma unroll
    for (int j = 0; j < 2; ++j)
#pragma unroll
      for (int m = 0; m < M; ++m) {
        acc[m][j] = __builtin_amdgcn_mfma_f32_16x16x32_bf16(aA[c][m], bh[j], acc[m][j], 0, 0, 0);
        acc[m][j] = __builtin_amdgcn_mfma_f32_16x16x32_bf16(aA[c][m], bl[j], acc[m][j], 0, 0, 0);
      }
    __builtin_amdgcn_s_setprio(0);
  }

  // epilogue: BN + LIF
#pragma unroll
  for (int j = 0; j < 2; ++j) {
    int c = co0 + j * 16 + l15;
    float ga = bnt[c], mu = bnt[Co + c], va = bnt[2 * Co + c];
    float sc = ga / sqrtf(va + BNEPS);
#pragma unroll
    for (int m = 0; m < M; ++m) {
      int pixb = p0 + m * 16 + 4 * g;
#pragma unroll
      for (int r = 0; r < 4; ++r) {
        size_t idx = (size_t)(pixb + r) * Co + c;
        float bno = (acc[m][j][r] - mu) * sc;
        float mv = LEAK * mem[idx] + bno;
        float s = (mv > THRS) ? 1.0f : 0.0f;
        actout[idx] = __float2bfloat16(s);
        mem[idx] = mv - s;
      }
    }
  }
}

// Implicit-GEMM conv3x3(pad==dil) + BN + LIF (generic layers) — r12 structure.
template<int M, int N, int GRP, int CPT, int SPLIT>
__global__ __launch_bounds__(SPLIT * 256, 4) void gemm_lif(
    const __hip_bfloat16* __restrict__ actin,
    const __hip_bfloat16* __restrict__ wsp,      // [2][Co][Kpad] hi, lo
    const float* __restrict__ bnt,               // [3][Co] for this timestep
    float* __restrict__ mem, __hip_bfloat16* __restrict__ actout,
    const __hip_bfloat16* __restrict__ zp,       // zero page (>= Cip bf16, zeroed)
    int Co, int lgHW, int lgW, int dil, int lgGX) {
  constexpr int NW = 4;
  constexpr int Cip = CPT * 32;
  constexpr int Kpad = 9 * Cip;
  constexpr int lgcpt = (CPT == 1) ? 0 : (CPT == 2) ? 1 : (CPT == 4) ? 2 : 3;
  constexpr int R  = N * 32;
  constexpr int lgR = (N == 1) ? 5 : ((N == 2) ? 6 : 7);
  constexpr int BUFROWS = GRP * R;
  constexpr int BUFELEM = BUFROWS * 32;
  constexpr int INSTS = BUFROWS / (16 * NW);
  constexpr int AM = M * GRP;
  constexpr int WAITN = AM;
  constexpr int NCH = (9 * CPT) / SPLIT;
  constexpr int NGRP = NCH / GRP;
  static_assert(NCH % GRP == 0, "group must divide per-half chunk count");
  __shared__ __hip_bfloat16 lds[SPLIT * 2 * BUFELEM];

  const int HW = 1 << lgHW, H = HW >> lgW, W = 1 << lgW;
  const unsigned CoKpad = (unsigned)Co * Kpad;
  const int lane = threadIdx.x & 63, wid = threadIdx.x >> 6;
  const int kw = wid >> 2;
  const int wq = wid & 3;
  const int l15 = lane & 15, g = lane >> 4;
  __hip_bfloat16* ldsh = lds + kw * 2 * BUFELEM;

  const int nb = gridDim.x;
  const int flat = blockIdx.x;
  const int swz = (flat & 7) * (nb >> 3) + (flat >> 3);
  const int bx = swz & ((1 << lgGX) - 1);
  const int by = swz >> lgGX;
  const int p0  = (bx * NW + wq) * (M * 16);
  const int co0 = by * (N * 16);

  int b_[M], y_[M], x_[M];
#pragma unroll
  for (int m = 0; m < M; ++m) {
    int pb = p0 + m * 16;
    b_[m] = pb >> lgHW;
    int rem = pb & (HW - 1);
    y_[m] = rem >> lgW;
    x_[m] = (rem & (W - 1)) + l15;
  }

  const unsigned kbase = (unsigned)kw * (NCH * 32);
  unsigned sgb[INSTS];
#pragma unroll
  for (int i = 0; i < INSTS; ++i) {
    int f  = wq * (BUFROWS / NW) + i * 16 + (lane >> 2);
    int cc = f >> lgR;
    int r  = f & (R - 1);
    int half = r >> (lgR - 1);
    int co   = r & (16 * N - 1);
    int slot = (lane & 3) ^ ((co >> 1) & 3);
    sgb[i] = (unsigned)half * CoKpad + (unsigned)(co0 + co) * Kpad + slot * 8
           + cc * 32 + kbase;
  }

  auto stage = [&](int gl, int buf) {
#pragma unroll
    for (int i = 0; i < INSTS; ++i) {
      const __hip_bfloat16* gp = wsp + sgb[i] + gl * (GRP * 32);
      __hip_bfloat16* lp = &ldsh[buf * BUFELEM + (wq * (BUFROWS / NW) + i * 16) * 32];
      __builtin_amdgcn_global_load_lds(
          (const __attribute__((address_space(1))) void*)gp,
          (__attribute__((address_space(3))) void*)lp, 16, 0, 0);
    }
  };

  const __hip_bfloat16* apc[M];
  auto mkaddr = [&](int tap) {
    int ty = (tap * 11) >> 5;
    int tx = tap - ty * 3;
    int dy = (ty - 1) * dil, dx = (tx - 1) * dil;
#pragma unroll
    for (int m = 0; m < M; ++m) {
      int sy = y_[m] + dy, sx = x_[m] + dx;
      bool v = (sy >= 0) & (sy < H) & (sx >= 0) & (sx < W);
      int pix = (b_[m] << lgHW) + (sy << lgW) + sx;
      apc[m] = v ? (actin + (size_t)pix * Cip + 8 * g) : (zp + 8 * g);
    }
  };

  auto prefA_slice = [&](int cg, int cc, short8v (&dst)[GRP][M], bool force) {
    if ((cg & (CPT - 1)) == 0 || force) mkaddr(cg >> lgcpt);
    int kc = (cg & (CPT - 1)) << 5;
#pragma unroll
    for (int m = 0; m < M; ++m)
      dst[cc][m] = *(const short8v*)(apc[m] + kc);
  };

  f32x4 acc[M][N] = {};
  const int rdb = l15 * 32 + ((g ^ ((l15 >> 1) & 3)) * 8);

  short8v aA[GRP][M], aB[GRP][M];

  auto grp_body = [&](int gi, short8v (&aU)[GRP][M], short8v (&aF)[GRP][M]) {
    asm volatile("s_waitcnt vmcnt(%0)" :: "n"(WAITN) : "memory");
    __builtin_amdgcn_s_barrier();
    __builtin_amdgcn_sched_barrier(0);

    const bool more = (gi + 1 < NGRP);
    if (more) stage(gi + 1, (gi + 1) & 1);

    const __hip_bfloat16* bp = &ldsh[(gi & 1) * BUFELEM];
#pragma unroll
    for (int cc = 0; cc < GRP; ++cc) {
      if (more) prefA_slice(kw * NCH + (gi + 1) * GRP + cc, cc, aF, false);
      short8v bh[N], bl[N];
#pragma unroll
      for (int j = 0; j < N; ++j) {
        bh[j] = *(const short8v*)(bp + cc * (R * 32) + j * 512 + rdb);
        bl[j] = *(const short8v*)(bp + cc * (R * 32) + (N * 512) + j * 512 + rdb);
      }
      __builtin_amdgcn_s_setprio(1);
#pragma unroll
      for (int j = 0; j < N; ++j)
#pragma unroll
        for (int m = 0; m < M; ++m) {
          acc[m][j] = __builtin_amdgcn_mfma_f32_16x16x32_bf16(aU[cc][m], bh[j], acc[m][j], 0, 0, 0);
          acc[m][j] = __builtin_amdgcn_mfma_f32_16x16x32_bf16(aU[cc][m], bl[j], acc[m][j], 0, 0, 0);
        }
      __builtin_amdgcn_s_setprio(0);
    }
  };

  stage(0, 0);
#pragma unroll
  for (int cc = 0; cc < GRP; ++cc)
    prefA_slice(kw * NCH + cc, cc, aA, cc == 0);

#pragma unroll
  for (int gi = 0; gi < NGRP; ++gi) {
    if (gi & 1) grp_body(gi, aB, aA);
    else        grp_body(gi, aA, aB);
  }

  if constexpr (SPLIT == 2) {
    asm volatile("s_waitcnt vmcnt(0) lgkmcnt(0)" ::: "memory");
    __builtin_amdgcn_s_barrier();
    float* red = (float*)lds;
    const int tid = wq * 64 + lane;
    if (kw == 1) {
#pragma unroll
      for (int m = 0; m < M; ++m)
#pragma unroll
        for (int j = 0; j < N; ++j)
#pragma unroll
          for (int r = 0; r < 4; ++r)
            red[((m * N + j) * 4 + r) * 256 + tid] = acc[m][j][r];
    }
    asm volatile("s_waitcnt lgkmcnt(0)" ::: "memory");
    __builtin_amdgcn_s_barrier();
    if (kw == 1) return;
#pragma unroll
    for (int m = 0; m < M; ++m)
#pragma unroll
      for (int j = 0; j < N; ++j)
#pragma unroll
        for (int r = 0; r < 4; ++r)
          acc[m][j][r] += red[((m * N + j) * 4 + r) * 256 + tid];
  }

#pragma unroll
  for (int j = 0; j < N; ++j) {
    int c = co0 + j * 16 + l15;
    float ga = bnt[c], mu = bnt[Co + c], va = bnt[2 * Co + c];
    float sc = ga / sqrtf(va + BNEPS);
#pragma unroll
    for (int m = 0; m < M; ++m) {
      int pixb = p0 + m * 16 + 4 * g;
#pragma unroll
      for (int r = 0; r < 4; ++r) {
        size_t idx = (size_t)(pixb + r) * Co + c;
        float bno = (acc[m][j][r] - mu) * sc;
        float mv = LEAK * mem[idx] + bno;
        float s = (mv > THRS) ? 1.0f : 0.0f;
        actout[idx] = __float2bfloat16(s);
        mem[idx] = mv - s;
      }
    }
  }
}

// AvgPool(3,2,1) storing SUM (exact ints in bf16); /9 folded into next layer weights.
__global__ void avgpool_sum8(const __hip_bfloat16* __restrict__ in,
                             __hip_bfloat16* __restrict__ out, int C, int H, int W) {
  const int Ho = H >> 1, Wo = W >> 1;
  const int C8 = C >> 3;
  const int n = BB * Ho * Wo * C8;
  int i = blockIdx.x * 256 + threadIdx.x;
  if (i >= n) return;
  int c8 = i % C8; int t = i / C8;
  int xo = t % Wo; t /= Wo;
  int yo = t % Ho; int b = t / Ho;
  const int y0 = 2 * yo - 1, x0 = 2 * xo - 1;
  float s[8] = {0, 0, 0, 0, 0, 0, 0, 0};
#pragma unroll
  for (int dy = 0; dy < 3; ++dy) {
    int iy = y0 + dy;
    if (iy < 0 || iy >= H) continue;
#pragma unroll
    for (int dx = 0; dx < 3; ++dx) {
      int ix = x0 + dx;
      if (ix < 0 || ix >= W) continue;
      short8v v = *(const short8v*)(in + (((size_t)b * H + iy) * W + ix) * C + c8 * 8);
#pragma unroll
      for (int e = 0; e < 8; ++e) {
        __hip_bfloat16_raw raw; raw.x = (unsigned short)v[e];
        s[e] += __bfloat162float(__hip_bfloat16(raw));
      }
    }
  }
  short8v o;
#pragma unroll
  for (int e = 0; e < 8; ++e) {
    __hip_bfloat16_raw raw = __hip_bfloat16_raw(__float2bfloat16(s[e]));
    o[e] = (short)raw.x;
  }
  *(short8v*)(out + (size_t)i * 8) = o;
}

// 1x1 conv 1024->21 @32x32, f32, accumulate into d_out. One wave per (b,pix).
__global__ void out_conv(const __hip_bfloat16* __restrict__ act,  // [B*1024px][1024ch]
                         const float* __restrict__ W8, float* __restrict__ out) {
  int gw = (blockIdx.x * 256 + threadIdx.x) >> 6;  // b*1024 + pix
  int lane = threadIdx.x & 63;
  int b = gw >> 10, pix = gw & 1023;
  const __hip_bfloat16* ap = act + ((size_t)gw << 10);
  float acc[NCLS];
#pragma unroll
  for (int c = 0; c < NCLS; ++c) acc[c] = 0.0f;
  for (int j = 0; j < 16; ++j) {
    int ci = j * 64 + lane;
    float av = __bfloat162float(ap[ci]);
#pragma unroll
    for (int c = 0; c < NCLS; ++c) acc[c] = fmaf(av, W8[c * 1024 + ci], acc[c]);
  }
#pragma unroll
  for (int c = 0; c < NCLS; ++c) {
    float v = acc[c];
    for (int off = 32; off; off >>= 1) v += __shfl_xor(v, off, 64);
    if (lane == 0) out[((size_t)b * NCLS + c) * 1024 + pix] += v;
  }
}

extern "C" void kernel_launch(void* const* d_in, const int* in_sizes, int n_in,
                              void* d_out, int out_size, void* d_ws, size_t ws_size,
                              hipStream_t stream) {
  const float* x = (const float*)d_in[0];
  const float* u = (const float*)d_in[1];
  const float* Wc[9];
  for (int i = 0; i < 9; ++i) Wc[i] = (const float*)d_in[2 + i];
  const float* bn[8];
  for (int i = 0; i < 8; ++i) bn[i] = (const float*)d_in[11 + i];

  // generic layers 1..7 geometry (index 0 unused for weights: packed separately)
  const int Ci_[8]  = {3, 64, 64, 128, 128, 256, 256, 256};
  const int Cip_[8] = {8, 64, 64, 128, 128, 256, 256, 256};
  const int Co_[8]  = {64, 64, 128, 128, 256, 256, 256, 1024};
  const int HH_[8]  = {128, 128, 64, 64, 32, 32, 32, 32};
  const float wsc_[8] = {1.f, 1.f, 1.f / 9.f, 1.f, 1.f / 9.f, 1.f, 1.f, 1.f};

  float* ws = (float*)d_ws;
  size_t off = 0;
  auto align8 = [](size_t v) { return (v + 7) & ~(size_t)7; };

  float* memp[8];
  for (int i = 0; i < 8; ++i) {
    memp[i] = ws + off;
    off += (size_t)BB * HH_[i] * HH_[i] * Co_[i];
  }
  __hip_bfloat16* zp = (__hip_bfloat16*)(ws + off);   // zero page (1 KB)
  off += 256;
  const size_t zero_floats = off;                     // mem + zp zeroed each call
  __hip_bfloat16* spk = (__hip_bfloat16*)(ws + off);  // [B*HW][8], fully written each step
  off += (size_t)BB * 16384 * 8 / 2;
  __hip_bfloat16* actA = (__hip_bfloat16*)(ws + off); off += 2097152;
  __hip_bfloat16* actB = (__hip_bfloat16*)(ws + off); off += 2097152;
  __hip_bfloat16* wall[8];
  // L0 packed: [2][64][96]
  wall[0] = (__hip_bfloat16*)(ws + off);
  off = align8(off + (size_t)64 * 96);                // hi+lo = 2*6144 bf16 = 6144 floats
  for (int i = 1; i < 8; ++i) {
    size_t n = (size_t)Co_[i] * 9 * Cip_[i];          // per half
    wall[i] = (__hip_bfloat16*)(ws + off);
    off = align8(off + n);                            // hi + lo = n floats
  }

  zero_f32<<<2048, 256, 0, stream>>>(ws, (int)zero_floats);
  zero_f32<<<(BB * NCLS * 1024 + 255) / 256, 256, 0, stream>>>((float*)d_out, BB * NCLS * 1024);

  wsplit_l0<<<(64 * 96 + 255) / 256, 256, 0, stream>>>(Wc[0], wall[0], wall[0] + 64 * 96);
  for (int i = 1; i < 8; ++i) {
    int n = Co_[i] * 9 * Cip_[i];
    wsplit<<<(n + 255) / 256, 256, 0, stream>>>(Wc[i], wall[i], wall[i] + n,
                                                Co_[i], Ci_[i], Cip_[i], wsc_[i]);
  }

  const size_t uT = (size_t)BB * 3 * 16384;
  for (int t = 0; t < TT; ++t) {
    spike_gen8<<<(BB * 16384 + 255) / 256, 256, 0, stream>>>(x, u + (size_t)t * uT, spk);
    // L0: tap-packed, grid 1024 (4 waves/SIMD), K=96
    gemm_lif_l0<<<1024, 256, 0, stream>>>(spk, wall[0], bn[0] + (size_t)t * 3 * 64, memp[0], actA, zp);
    // L1: 64->64 @128      wave 32x32, grid 1024
    gemm_lif<2, 2, 3, 2, 1><<<1024, 256, 0, stream>>>(actA, wall[1], bn[1] + (size_t)t * 3 * 64,   memp[1], actB, zp, 64,   14, 7, 1, 9);
    avgpool_sum8<<<(BB * 64 * 64 * 8 + 255) / 256, 256, 0, stream>>>(actB, actA, 64, 128, 128);
    // L2: 64->128 @64 (w/9)  wave 32x32, split-K x2, 512 blk x 512 thr
    gemm_lif<2, 2, 3, 2, 2><<<512, 512, 0, stream>>>(actA, wall[2], bn[2] + (size_t)t * 3 * 128,  memp[2], actB, zp, 128,  12, 6, 1, 7);
    // L3: 128->128 @64       split-K x2
    gemm_lif<2, 2, 3, 4, 2><<<512, 512, 0, stream>>>(actB, wall[3], bn[3] + (size_t)t * 3 * 128,  memp[3], actA, zp, 128,  12, 6, 1, 7);
    avgpool_sum8<<<(BB * 32 * 32 * 16 + 255) / 256, 256, 0, stream>>>(actA, actB, 128, 64, 64);
    // L4: 128->256 @32 (w/9) wave 16x32, split-K x2
    gemm_lif<1, 2, 3, 4, 2><<<512, 512, 0, stream>>>(actB, wall[4], bn[4] + (size_t)t * 3 * 256,   memp[4], actA, zp, 256,  10, 5, 1, 6);
    // L5: 256->256 @32 dil2  split-K x2
    gemm_lif<1, 2, 4, 8, 2><<<512, 512, 0, stream>>>(actA, wall[5], bn[5] + (size_t)t * 3 * 256,   memp[5], actB, zp, 256,  10, 5, 2, 6);
    // L6: 256->256 @32 dil2  split-K x2
    gemm_lif<1, 2, 4, 8, 2><<<512, 512, 0, stream>>>(actB, wall[6], bn[6] + (size_t)t * 3 * 256,   memp[6], actA, zp, 256,  10, 5, 2, 6);
    // L7: 256->1024 @32 dil12  wave 32x64, split-K x2
    gemm_lif<2, 4, 2, 8, 2><<<512, 512, 0, stream>>>(actA, wall[7], bn[7] + (size_t)t * 3 * 1024, memp[7], actB, zp, 1024, 10, 5, 12, 5);
    // output layer accumulation
    out_conv<<<dim3(BB * 1024 / 4), 256, 0, stream>>>(actB, Wc[8], (float*)d_out);
  }
  scale_f32<<<(BB * NCLS * 1024 + 255) / 256, 256, 0, stream>>>((float*)d_out, BB * NCLS * 1024, 1.0f / TT);
}